// Round 18
// baseline (440.777 us; speedup 1.0000x reference)
//
#include <hip/hip_runtime.h>
#include <math.h>

#define Hh 8
#define Bb 16
#define Nn 512
#define Dd 512
#define VDd 64
#define NPICKk 256
#define NORMF 0.125f
#define SCL2 0.1803368801f   /* NORMF * log2(e) */

typedef unsigned short ushortT;
typedef __bf16 bf16x8 __attribute__((ext_vector_type(8)));
typedef float f32x4 __attribute__((ext_vector_type(4)));

struct PtrsB { const ushortT* p[12]; };
struct PtrsD { ushortT* p[6]; };
struct Ptrs9 { const float* p[9]; };
struct Ptrs10 { const float* p[10]; };
struct Ptrs6 { const float* p[6]; };

__device__ inline ushortT f2bf(float f) {
    __bf16 h = (__bf16)f;
    union { __bf16 h; ushortT u; } v; v.h = h;
    return v.u;
}
__device__ inline float bf2f(ushortT u) {
    union { unsigned int u; float f; } v; v.u = ((unsigned int)u) << 16;
    return v.f;
}
__device__ inline float exp2fast(float x) {
#if __has_builtin(__builtin_amdgcn_exp2f)
    return __builtin_amdgcn_exp2f(x);
#else
    return exp2f(x);
#endif
}
__device__ inline void gload16(const void* gptr, void* ldsptr) {
    auto g = reinterpret_cast<const __attribute__((address_space(1))) unsigned int*>(
        reinterpret_cast<uintptr_t>(gptr));
    auto l = reinterpret_cast<__attribute__((address_space(3))) unsigned int*>(
        reinterpret_cast<uintptr_t>(ldsptr));
    __builtin_amdgcn_global_load_lds(g, l, 16, 0, 0);
}

#define LIX(r, g) (((r) << 6) + ((((g) ^ ((r) & 7))) << 3))
// 32-col bf16 tile (64B rows): group g (0..3), swizzle over (row>>1)&3
#define LIX2(r, g) (((r) << 5) + ((((g) ^ (((r) >> 1) & 3))) << 3))

// ---------- fp32 -> bf16 elementwise ----------
__global__ __launch_bounds__(256) void castx(const float* __restrict__ in,
                                             ushortT* __restrict__ out) {
    int i = blockIdx.x * 256 + threadIdx.x;
    float4 v = *(const float4*)&in[(size_t)i * 4];
    ushort4 o; o.x = f2bf(v.x); o.y = f2bf(v.y); o.z = f2bf(v.z); o.w = f2bf(v.w);
    *(ushort4*)&out[(size_t)i * 4] = o;
}

// ---------- transpose+cast body ----------
__device__ inline void tbody(const float* __restrict__ in, ushortT* __restrict__ out,
                             int in_ld, int out_ld, int r0, int c0) {
    __shared__ float T[64][65];
    int tr = threadIdx.x >> 4, tc4 = (threadIdx.x & 15) * 4;
#pragma unroll
    for (int p = 0; p < 4; ++p) {
        float4 v = *(const float4*)&in[(size_t)(r0 + tr + p * 16) * in_ld + c0 + tc4];
        T[tr + p * 16][tc4 + 0] = v.x; T[tr + p * 16][tc4 + 1] = v.y;
        T[tr + p * 16][tc4 + 2] = v.z; T[tr + p * 16][tc4 + 3] = v.w;
    }
    __syncthreads();
#pragma unroll
    for (int p = 0; p < 4; ++p) {
        int orow = c0 + tr + p * 16;
        int ocol = r0 + tc4;
        ushort4 o;
        o.x = f2bf(T[tc4 + 0][tr + p * 16]);
        o.y = f2bf(T[tc4 + 1][tr + p * 16]);
        o.z = f2bf(T[tc4 + 2][tr + p * 16]);
        o.w = f2bf(T[tc4 + 3][tr + p * 16]);
        *(ushort4*)&out[(size_t)orow * out_ld + ocol] = o;
    }
}

__global__ __launch_bounds__(256) void thead(Ptrs9 s, ushortT* __restrict__ dst) {
    int w = blockIdx.z >> 3, h = blockIdx.z & 7;
    tbody(s.p[w] + (size_t)h * 512 * 64,
          dst + (size_t)w * 262144 + (size_t)h * 64 * 512,
          64, 512, blockIdx.y * 64, 0);
}
__global__ __launch_bounds__(256) void tsq(Ptrs10 s, ushortT* __restrict__ dst) {
    tbody(s.p[blockIdx.z], dst + (size_t)blockIdx.z * 262144,
          512, 512, blockIdx.y * 64, blockIdx.x * 64);
}
__global__ __launch_bounds__(256) void tff(Ptrs6 s, ushortT* __restrict__ dst) {
    int z = blockIdx.z;
    if (z < 3) { if (blockIdx.y >= 8 || blockIdx.x >= 32) return; }
    else       { if (blockIdx.y >= 32 || blockIdx.x >= 8) return; }
    int in_ld = (z < 3) ? 2048 : 512;
    int out_ld = (z < 3) ? 512 : 2048;
    tbody(s.p[z], dst + (size_t)z * 1048576, in_ld, out_ld,
          blockIdx.y * 64, blockIdx.x * 64);
}

// ---------- 128x128 bf16 MFMA GEMM: 4-slot BK=32 ring, ONE barrier/sub-tile ----------
__global__ __launch_bounds__(256) void gemm_bf(
    PtrsB Bp, PtrsD Db, const ushortT* __restrict__ A, float* __restrict__ outF,
    int M, int N, int K, const float* __restrict__ bias,
    const float* __restrict__ res, const float* __restrict__ alpha,
    int do_relu, int nroute, int vtmask, int scmask)
{
    __shared__ __align__(16) ushortT As[4][128 * 32];   // 32 KB ring
    __shared__ __align__(16) ushortT Bs[4][128 * 32];   // 32 KB ring
    const int tid = threadIdx.x;
    const int wid = tid >> 6, lane = tid & 63;
    const int wm = wid >> 1, wn = wid & 1;
    const int l15 = lane & 15, l4 = lane >> 4;

    int bid = blockIdx.y * gridDim.x + blockIdx.x;
    int nwg = gridDim.x * gridDim.y;
    int q = nwg >> 3;
    int swz = (bid & 7) * q + (bid >> 3);
    int bx = swz % gridDim.x, by = swz / gridDim.x;

    const int r0 = by * 128, c0 = bx * 128;
    const int half = ((r0 & (Nn - 1)) >= NPICKk) ? 1 : 0;
    const ushortT* Bt = Bp.p[((c0 >> 9) << 1) | half];
    const int cB = nroute ? (c0 & 511) : c0;

    // BK=32 staging geometry (verified R15): per wave 2 x 1KB per matrix
    const ushortT* aSrc[2];
    const ushortT* bSrc[2];
    int offv[2];
#pragma unroll
    for (int i = 0; i < 2; ++i) {
        int off = wid * 2048 + i * 1024 + lane * 16;
        int row = off >> 6;
        int sg = ((off >> 4) & 3) ^ ((row >> 1) & 3);
        aSrc[i] = A + (size_t)(r0 + row) * K + sg * 8;
        bSrc[i] = Bt + (size_t)(cB + row) * K + sg * 8;
        offv[i] = off;
    }

    const int nkt = K >> 5;   // sub-tiles of BK=32 (16 for K=512, 64 for K=2048)
    // prologue: issue sub-tiles 0,1,2 (12 loads outstanding per wave)
#pragma unroll
    for (int tt = 0; tt < 3; ++tt)
#pragma unroll
        for (int i = 0; i < 2; ++i) {
            gload16(aSrc[i] + tt * 32, (char*)As[tt] + offv[i]);
            gload16(bSrc[i] + tt * 32, (char*)Bs[tt] + offv[i]);
        }

    f32x4 acc[4][4] = {};

    for (int t = 0; t < nkt; ++t) {
        const int rem = nkt - 1 - t;   // sub-tiles already issued beyond t
        if (rem >= 2)      asm volatile("s_waitcnt vmcnt(8)" ::: "memory");
        else if (rem == 1) asm volatile("s_waitcnt vmcnt(4)" ::: "memory");
        else               asm volatile("s_waitcnt vmcnt(0)" ::: "memory");
        __builtin_amdgcn_s_barrier();   // slot t&3 staged (all waves); slot (t-1)&3 read-complete
        __builtin_amdgcn_sched_barrier(0);
        // refill t+3 into slot (t+3)&3 == (t-1)&3 (safe: read-complete after barrier)
        if (t + 3 < nkt) {
            int kt2 = (t + 3) << 5;
            int sl = (t + 3) & 3;
#pragma unroll
            for (int i = 0; i < 2; ++i) {
                gload16(aSrc[i] + kt2, (char*)As[sl] + offv[i]);
                gload16(bSrc[i] + kt2, (char*)Bs[sl] + offv[i]);
            }
        }
        const ushortT* Ac = As[t & 3];
        const ushortT* Bc = Bs[t & 3];
        __builtin_amdgcn_s_setprio(1);
        {
            bf16x8 af[4], bfv[4];
#pragma unroll
            for (int mi = 0; mi < 4; ++mi)
                af[mi] = *(const bf16x8*)&Ac[LIX2(wm * 64 + mi * 16 + l15, l4)];
#pragma unroll
            for (int ni = 0; ni < 4; ++ni)
                bfv[ni] = *(const bf16x8*)&Bc[LIX2(wn * 64 + ni * 16 + l15, l4)];
#pragma unroll
            for (int mi = 0; mi < 4; ++mi)
#pragma unroll
                for (int ni = 0; ni < 4; ++ni)
                    acc[mi][ni] = __builtin_amdgcn_mfma_f32_16x16x32_bf16(
                        bfv[ni], af[mi], acc[mi][ni], 0, 0, 0);   // C^T fragment
        }
        __builtin_amdgcn_s_setprio(0);
    }

    if (nroute) {
#pragma unroll
        for (int mi = 0; mi < 4; ++mi) {
            int row = r0 + wm * 64 + mi * 16 + l15;
#pragma unroll
            for (int ni = 0; ni < 4; ++ni) {
                int col = c0 + wn * 64 + ni * 16 + l4 * 4;
                int range = col >> 9, cc = col & 511;
                ushortT* d = Db.p[range];
                f32x4 a = acc[mi][ni];
                if ((scmask >> range) & 1) {
                    a[0] *= SCL2; a[1] *= SCL2; a[2] *= SCL2; a[3] *= SCL2;
                }
                if ((vtmask >> range) & 1) {
                    size_t vb = ((size_t)(row >> 9) * Hh + (cc >> 6)) * 64 + (cc & 63);
                    int tok = row & 511;
#pragma unroll
                    for (int r = 0; r < 4; ++r)
                        d[((vb + r) << 9) + tok] = f2bf(a[r]);
                } else {
                    ushort4 o;
                    o.x = f2bf(a[0]); o.y = f2bf(a[1]);
                    o.z = f2bf(a[2]); o.w = f2bf(a[3]);
                    *(ushort4*)&d[((size_t)row << 9) + cc] = o;
                }
            }
        }
    } else {
        const float alp = alpha ? alpha[0] : 1.0f;
        ushortT* outB = Db.p[0];
#pragma unroll
        for (int mi = 0; mi < 4; ++mi) {
            int row = r0 + wm * 64 + mi * 16 + l15;
#pragma unroll
            for (int ni = 0; ni < 4; ++ni) {
                int colb = c0 + wn * 64 + ni * 16 + l4 * 4;
                f32x4 a = acc[mi][ni];
                if (bias) {
                    float4 b4 = *(const float4*)&bias[colb];
                    a[0] += b4.x; a[1] += b4.y; a[2] += b4.z; a[3] += b4.w;
                }
                if (do_relu) {
#pragma unroll
                    for (int r = 0; r < 4; ++r) a[r] = fmaxf(a[r], 0.f);
                }
#pragma unroll
                for (int r = 0; r < 4; ++r) a[r] *= alp;
                size_t idx = (size_t)row * N + colb;
                if (res) {
                    float4 r4 = *(const float4*)&res[idx];
                    a[0] += r4.x; a[1] += r4.y; a[2] += r4.z; a[3] += r4.w;
                }
                if (outF)
                    *(float4*)&outF[idx] = make_float4(a[0], a[1], a[2], a[3]);
                if (outB) {
                    ushort4 o;
                    o.x = f2bf(a[0]); o.y = f2bf(a[1]);
                    o.z = f2bf(a[2]); o.w = f2bf(a[3]);
                    *(ushort4*)&outB[idx] = o;
                }
            }
        }
    }
}

// ---------- 64x128 bf16 MFMA GEMM, T4 double-buffer + T5; res f32/bf16 ----------
__global__ __launch_bounds__(256) void gemm64(
    const ushortT* __restrict__ Bw, const ushortT* __restrict__ A,
    float* __restrict__ outF, ushortT* __restrict__ outB,
    int M, int N, int K, const float* __restrict__ bias,
    const float* __restrict__ resf, const ushortT* __restrict__ resb,
    const float* __restrict__ alpha, int do_relu)
{
    __shared__ __align__(16) ushortT As[2][64 * 64];    // 16 KB
    __shared__ __align__(16) ushortT Bs[2][128 * 64];   // 32 KB
    const int tid = threadIdx.x;
    const int wid = tid >> 6, lane = tid & 63;
    const int wm = wid >> 1, wn = wid & 1;
    const int l15 = lane & 15, l4 = lane >> 4;

    int bid = blockIdx.y * gridDim.x + blockIdx.x;
    int nwg = gridDim.x * gridDim.y;
    int q = nwg >> 3;
    int swz = (bid & 7) * q + (bid >> 3);
    int bx = swz % gridDim.x, by = swz / gridDim.x;
    const int r0 = by * 64, c0 = bx * 128;

    const ushortT* aSrc[2];
    int offA[2];
#pragma unroll
    for (int i = 0; i < 2; ++i) {
        int off = wid * 2048 + i * 1024 + lane * 16;
        int row = off >> 7;
        int sg = ((off >> 4) & 7) ^ (row & 7);
        aSrc[i] = A + (size_t)(r0 + row) * K + sg * 8;
        offA[i] = off;
    }
    const ushortT* bSrc[4];
    int offB[4];
#pragma unroll
    for (int i = 0; i < 4; ++i) {
        int off = wid * 4096 + i * 1024 + lane * 16;
        int row = off >> 7;
        int sg = ((off >> 4) & 7) ^ (row & 7);
        bSrc[i] = Bw + (size_t)(c0 + row) * K + sg * 8;
        offB[i] = off;
    }

    const int nkt = K >> 6;
#pragma unroll
    for (int i = 0; i < 2; ++i) gload16(aSrc[i], (char*)As[0] + offA[i]);
#pragma unroll
    for (int i = 0; i < 4; ++i) gload16(bSrc[i], (char*)Bs[0] + offB[i]);
#pragma unroll
    for (int i = 0; i < 2; ++i) gload16(aSrc[i] + 64, (char*)As[1] + offA[i]);
#pragma unroll
    for (int i = 0; i < 4; ++i) gload16(bSrc[i] + 64, (char*)Bs[1] + offB[i]);

    f32x4 acc[2][4] = {};

    for (int t = 0; t < nkt; ++t) {
        const int cur = t & 1;
        if (t == nkt - 1) asm volatile("s_waitcnt vmcnt(0)" ::: "memory");
        else              asm volatile("s_waitcnt vmcnt(6)" ::: "memory");
        __builtin_amdgcn_s_barrier();
        __builtin_amdgcn_sched_barrier(0);
        const ushortT* Ac = As[cur];
        const ushortT* Bc = Bs[cur];
        __builtin_amdgcn_s_setprio(1);
#pragma unroll
        for (int kk = 0; kk < 2; ++kk) {
            int g0 = kk * 4 + l4;
            bf16x8 af[2], bfv[4];
#pragma unroll
            for (int mi = 0; mi < 2; ++mi)
                af[mi] = *(const bf16x8*)&Ac[LIX(wm * 32 + mi * 16 + l15, g0)];
#pragma unroll
            for (int ni = 0; ni < 4; ++ni)
                bfv[ni] = *(const bf16x8*)&Bc[LIX(wn * 64 + ni * 16 + l15, g0)];
#pragma unroll
            for (int mi = 0; mi < 2; ++mi)
#pragma unroll
                for (int ni = 0; ni < 4; ++ni)
                    acc[mi][ni] = __builtin_amdgcn_mfma_f32_16x16x32_bf16(
                        bfv[ni], af[mi], acc[mi][ni], 0, 0, 0);
        }
        __builtin_amdgcn_s_setprio(0);
        __builtin_amdgcn_s_barrier();
        asm volatile("" ::: "memory");
        if (t + 2 < nkt) {
            int kt2 = (t + 2) << 6;
#pragma unroll
            for (int i = 0; i < 2; ++i) gload16(aSrc[i] + kt2, (char*)As[cur] + offA[i]);
#pragma unroll
            for (int i = 0; i < 4; ++i) gload16(bSrc[i] + kt2, (char*)Bs[cur] + offB[i]);
        }
    }

    const float alp = alpha ? alpha[0] : 1.0f;
#pragma unroll
    for (int mi = 0; mi < 2; ++mi) {
        int row = r0 + wm * 32 + mi * 16 + l15;
#pragma unroll
        for (int ni = 0; ni < 4; ++ni) {
            int colb = c0 + wn * 64 + ni * 16 + l4 * 4;
            f32x4 a = acc[mi][ni];
            if (bias) {
                float4 b4 = *(const float4*)&bias[colb];
                a[0] += b4.x; a[1] += b4.y; a[2] += b4.z; a[3] += b4.w;
            }
            if (do_relu) {
#pragma unroll
                for (int r = 0; r < 4; ++r) a[r] = fmaxf(a[r], 0.f);
            }
#pragma unroll
            for (int r = 0; r < 4; ++r) a[r] *= alp;
            size_t idx = (size_t)row * N + colb;
            if (resf) {
                float4 r4 = *(const float4*)&resf[idx];
                a[0] += r4.x; a[1] += r4.y; a[2] += r4.z; a[3] += r4.w;
            }
            if (resb) {
                ushort4 r4 = *(const ushort4*)&resb[idx];
                a[0] += bf2f(r4.x); a[1] += bf2f(r4.y);
                a[2] += bf2f(r4.z); a[3] += bf2f(r4.w);
            }
            if (outF)
                *(float4*)&outF[idx] = make_float4(a[0], a[1], a[2], a[3]);
            if (outB) {
                ushort4 o;
                o.x = f2bf(a[0]); o.y = f2bf(a[1]);
                o.z = f2bf(a[2]); o.w = f2bf(a[3]);
                *(ushort4*)&outB[idx] = o;
            }
        }
    }
}

// ---------- HA diagonal scores (QD pre-scaled by NORM*log2e) ----------
__global__ __launch_bounds__(256) void diag_dot_bb(const ushortT* __restrict__ QD,
                                                   const ushortT* __restrict__ K,
                                                   float* __restrict__ Sdg) {
    int i = blockIdx.x * 256 + threadIdx.x;
    int h = i & 7, n = (i >> 3) & 511, b = i >> 12;
    int dix = (n < NPICKk) ? n + NPICKk : n - NPICKk;
    const ushortT* q = QD + (((size_t)(b * Nn + n) * Hh + h) << 6);
    const ushortT* k = K + (((size_t)(b * Nn + dix) * Hh + h) << 6);
    float s = 0.f;
#pragma unroll
    for (int d = 0; d < 64; d += 4) {
        ushort4 a = *(const ushort4*)(q + d);
        ushort4 c = *(const ushort4*)(k + d);
        s += bf2f(a.x) * bf2f(c.x) + bf2f(a.y) * bf2f(c.y)
           + bf2f(a.z) * bf2f(c.z) + bf2f(a.w) * bf2f(c.w);
    }
    Sdg[i] = s;
}

// ---------- flash attention: T14 reg-staged double-buffered K/V, lazy max, deferred L ----------
template <int HA>
__global__ __launch_bounds__(256) void attn10(
    const ushortT* __restrict__ Qm, const ushortT* __restrict__ Km,
    const ushortT* __restrict__ Vtm, const ushortT* __restrict__ QAm,
    const ushortT* __restrict__ QBm, const float* __restrict__ Sdg,
    ushortT* __restrict__ Out)
{
    __shared__ __align__(16) ushortT Ks[64 * 64];
    __shared__ __align__(16) ushortT Vs[64 * 64];
    __shared__ __align__(16) ushortT Pw[4][16 * 64];
    __shared__ float sdl[64];

    const int tid = threadIdx.x, wid = tid >> 6, lane = tid & 63;
    const int l15 = lane & 15, l4 = lane >> 4;

    const int p = blockIdx.x + (blockIdx.y << 3) + (blockIdx.z << 6);
    const int n0 = (((p >> 3) & 7)) << 6;
    const int g8 = (p & 7) | ((p >> 6) << 3);
    const int h = g8 & 7, b = g8 >> 3;
    const int bh = b * Hh + h;

    const size_t qrow = (((size_t)(b * Nn + n0 + wid * 16 + l15) * Hh + h) << 6);
    bf16x8 qf[2], xaf[2], xbf[2];
#pragma unroll
    for (int kk = 0; kk < 2; ++kk) {
        int g0 = kk * 4 + l4;
        qf[kk] = *(const bf16x8*)&Qm[qrow + g0 * 8];
        if (HA) {
            xaf[kk] = *(const bf16x8*)&QAm[qrow + g0 * 8];
            xbf[kk] = *(const bf16x8*)&QBm[qrow + g0 * 8];
        }
    }
    if (HA && tid < 64) sdl[tid] = Sdg[((size_t)(b * Nn + n0 + tid)) * Hh + h];
    const int td = (n0 < NPICKk) ? ((n0 + NPICKk) >> 6) : ((n0 - NPICKk) >> 6);

    const ushortT* kSrc[2]; ushortT* kDst[2];
    const ushortT* vSrc[2]; ushortT* vDst[2];
#pragma unroll
    for (int i = 0; i < 2; ++i) {
        int off = wid * 2048 + i * 1024 + lane * 16;
        int row = off >> 7, sg = ((off >> 4) & 7) ^ (row & 7);
        kSrc[i] = Km + (((size_t)(b * Nn + row) * Hh + h) << 6) + sg * 8;
        kDst[i] = (ushortT*)((char*)Ks + off);
        vSrc[i] = Vtm + (((size_t)(bh * 64 + row)) << 9) + sg * 8;
        vDst[i] = (ushortT*)((char*)Vs + off);
    }

    float M[4], Lp[4];
    f32x4 Oa[4] = {};
#pragma unroll
    for (int r = 0; r < 4; ++r) { M[r] = -INFINITY; Lp[r] = 0.f; }

    bf16x8 krbuf[2][2], vrbuf[2][2];
#pragma unroll
    for (int i = 0; i < 2; ++i) {
        krbuf[0][i] = *(const bf16x8*)kSrc[i];
        vrbuf[0][i] = *(const bf16x8*)vSrc[i];
    }

#pragma unroll
    for (int t = 0; t < 8; ++t) {
        const int cur = t & 1, nxt = cur ^ 1;
        __builtin_amdgcn_s_barrier();
#pragma unroll
        for (int i = 0; i < 2; ++i) {
            *(bf16x8*)kDst[i] = krbuf[cur][i];
            *(bf16x8*)vDst[i] = vrbuf[cur][i];
        }
        if (t < 7) {
#pragma unroll
            for (int i = 0; i < 2; ++i) {
                krbuf[nxt][i] = *(const bf16x8*)(kSrc[i] + (size_t)(t + 1) * (64 * Hh * VDd));
                vrbuf[nxt][i] = *(const bf16x8*)(vSrc[i] + (t + 1) * 64);
            }
        }
        asm volatile("s_waitcnt lgkmcnt(0)" ::: "memory");
        __builtin_amdgcn_s_barrier();
        __builtin_amdgcn_sched_barrier(0);

        __builtin_amdgcn_s_setprio(1);
        f32x4 s1[4] = {}, sX[4] = {};
#pragma unroll
        for (int kk = 0; kk < 2; ++kk) {
            bf16x8 aq = qf[kk];
            bf16x8 ax;
            if (HA) ax = (t >= 4) ? xbf[kk] : xaf[kk];
#pragma unroll
            for (int ni = 0; ni < 4; ++ni) {
                bf16x8 bk = *(const bf16x8*)&Ks[LIX(ni * 16 + l15, kk * 4 + l4)];
                s1[ni] = __builtin_amdgcn_mfma_f32_16x16x32_bf16(aq, bk, s1[ni], 0, 0, 0);
                if (HA)
                    sX[ni] = __builtin_amdgcn_mfma_f32_16x16x32_bf16(ax, bk, sX[ni], 0, 0, 0);
            }
        }
        __builtin_amdgcn_s_setprio(0);

        const bool dt = HA && (t == td);

        float mloc[4];
        bool grow = false;
#pragma unroll
        for (int r = 0; r < 4; ++r) {
            int rw = wid * 16 + l4 * 4 + r;
            float m = s1[0][r];
#pragma unroll
            for (int ni = 1; ni < 4; ++ni) m = fmaxf(m, s1[ni][r]);
            if (HA) {
#pragma unroll
                for (int ni = 0; ni < 4; ++ni) m = fmaxf(m, sX[ni][r]);
            }
            if (dt && l15 == l4 * 4 + r) m = fmaxf(m, sdl[rw]);
            mloc[r] = m;
            grow = grow || (m > M[r] + 8.f);
        }
        if (__any(grow)) {
#pragma unroll
            for (int r = 0; r < 4; ++r) {
                float m = mloc[r];
#pragma unroll
                for (int o = 8; o >= 1; o >>= 1) m = fmaxf(m, __shfl_xor(m, o, 16));
                float mn = fmaxf(M[r], m);
                float sc = exp2fast(M[r] - mn);
                M[r] = mn; Lp[r] *= sc;
#pragma unroll
                for (int ni = 0; ni < 4; ++ni) Oa[ni][r] *= sc;
            }
        }

#pragma unroll
        for (int r = 0; r < 4; ++r) {
            int rw = wid * 16 + l4 * 4 + r;
            float rs = 0.f;
#pragma unroll
            for (int ni = 0; ni < 4; ++ni) {
                float pv = exp2fast(s1[ni][r] - M[r]);
                if (HA) pv += exp2fast(sX[ni][r] - M[r]);
                if (dt && ni == wid && l15 == l4 * 4 + r) pv += exp2fast(sdl[rw] - M[r]);
                s1[ni][r] = pv;
                rs += pv;
            }
            Lp[r] += rs;
        }

#pragma unroll
        for (int ni = 0; ni < 4; ++ni)
#pragma unroll
            for (int r = 0; r < 4; ++r) {
                int prow = l4 * 4 + r;
                int col = ni * 16 + l15;
                Pw[wid][(prow << 6) + ((((col >> 3) ^ (prow & 7))) << 3) + (col & 7)] =
                    f2bf(s1[ni][r]);
            }

        __builtin_amdgcn_s_setprio(1);
#pragma unroll
        for (int kk = 0; kk < 2; ++kk) {
            int g0 = kk * 4 + l4;
            bf16x8 ap = *(const bf16x8*)&Pw[wid][LIX(l15, g0)];
#pragma unroll
            for (int ni = 0; ni < 4; ++ni) {
                bf16x8 bv = *(const bf16x8*)&Vs[LIX(ni * 16 + l15, g0)];
                Oa[ni] = __builtin_amdgcn_mfma_f32_16x16x32_bf16(ap, bv, Oa[ni], 0, 0, 0);
            }
        }
        __builtin_amdgcn_s_setprio(0);
    }

#pragma unroll
    for (int r = 0; r < 4; ++r) {
        float l = Lp[r];
#pragma unroll
        for (int o = 8; o >= 1; o >>= 1) l += __shfl_xor(l, o, 16);
        float inv = 1.0f / l;
        size_t obase = (((size_t)(b * Nn + n0 + wid * 16 + l4 * 4 + r) * Hh + h) << 6);
#pragma unroll
        for (int ni = 0; ni < 4; ++ni)
            Out[obase + ni * 16 + l15] = f2bf(Oa[ni][r] * inv);
    }
}

extern "C" void kernel_launch(void* const* d_in, const int* in_sizes, int n_in,
                              void* d_out, int out_size, void* d_ws, size_t ws_size,
                              hipStream_t stream)
{
    const float* x = (const float*)d_in[0];

    int dictOrder = (in_sizes[18] != 512);
    const float* comb_w  = (const float*)d_in[17];
    const float* comb2_w = (const float*)d_in[dictOrder ? 18 : 19];
    const float* comb3_w = (const float*)d_in[dictOrder ? 19 : 21];
    const float* comb_b  = (const float*)d_in[dictOrder ? 20 : 18];
    const float* comb2_b = (const float*)d_in[dictOrder ? 21 : 20];
    const float* comb3_b = (const float*)d_in[22];
    const float* alpha1 = (const float*)d_in[23];
    const float* alpha2 = (const float*)d_in[24];
    const float* alpha3 = (const float*)d_in[25];
    const float* ff1_w1 = (const float*)d_in[26];
    const float* ff1_b1 = (const float*)d_in[27];
    const float* ff1_w2 = (const float*)d_in[28];
    const float* ff1_b2 = (const float*)d_in[29];
    const float* ffa1   = (const float*)d_in[30];
    const float* ff2_w1 = (const float*)d_in[31];
    const float* ff2_b1 = (const float*)d_in[32];
    const float* ff2_w2 = (const float*)d_in[33];
    const float* ff2_b2 = (const float*)d_in[34];
    const float* ffa2   = (const float*)d_in[35];
    const float* ff3_w1 = (const float*)d_in[36];
    const float* ff3_b1 = (const float*)d_in[37];
    const float* ff3_w2 = (const float*)d_in[38];
    const float* ff3_b2 = (const float*)d_in[39];
    const float* ffa3   = (const float*)d_in[40];

    // ---- workspace layout (bytes) ----
    char* W = (char*)d_ws;
    ushortT* wbHead = (ushortT*)(W + 0);
    ushortT* wbMha  = (ushortT*)(W + 4718592);
    ushortT* wbComb = (ushortT*)(W + 8388608);
    ushortT* wbFf1  = (ushortT*)(W + 9961472);
    ushortT* wbFf2  = (ushortT*)(W + 16252928);
    ushortT* xbf    = (ushortT*)(W + 22544384);
    float*   Sd     = (float*)  (W + 30932992);
    ushortT* bufQ   = (ushortT*)(W + 31195136);
    ushortT* bufK   = (ushortT*)(W + 39583744);
    ushortT* bufVt  = (ushortT*)(W + 47972352);
    ushortT* bufQA  = (ushortT*)(W + 56360960);
    ushortT* bufQB  = (ushortT*)(W + 64749568);
    ushortT* bufQD  = (ushortT*)(W + 73138176);
    ushortT* hidden = (ushortT*)(W + 81526784);
    ushortT* curb   = (ushortT*)(W + 115081216);
    ushortT* bufHA  = xbf;
    float*   cur    = (float*)d_out;

    dim3 tb(256);
    const int TOK = Bb * Nn;  // 8192
    const size_t WS = 512 * 512;
    const size_t WF = 2048 * 512;

    // 1. casts / transposes (batched)
    hipLaunchKernelGGL(castx, dim3(TOK * 512 / 1024), tb, 0, stream, x, xbf);
    {
        Ptrs9 s; for (int i = 0; i < 9; ++i) s.p[i] = (const float*)d_in[1 + i];
        hipLaunchKernelGGL(thead, dim3(1, 8, 72), tb, 0, stream, s, wbHead);
    }
    {
        Ptrs10 s;
        for (int i = 0; i < 7; ++i) s.p[i] = (const float*)d_in[10 + i];
        s.p[7] = comb_w; s.p[8] = comb2_w; s.p[9] = comb3_w;
        hipLaunchKernelGGL(tsq, dim3(8, 8, 10), tb, 0, stream, s, wbMha);
    }
    {
        Ptrs6 s;
        s.p[0] = ff1_w1; s.p[1] = ff2_w1; s.p[2] = ff3_w1;
        s.p[3] = ff1_w2; s.p[4] = ff2_w2; s.p[5] = ff3_w2;
        hipLaunchKernelGGL(tff, dim3(32, 32, 6), tb, 0, stream, s, wbFf1);
    }

    auto gemm = [&](PtrsB Bp, PtrsD Db, const ushortT* A, float* oF,
                    int M, int Ncc, int Kc, const float* bias, const float* res,
                    const float* alp, int relu, int nroute, int vtmask, int scmask) {
        hipLaunchKernelGGL(gemm_bf, dim3(Ncc / 128, M / 128), tb, 0, stream,
                           Bp, Db, A, oF, M, Ncc, Kc, bias, res, alp, relu, nroute,
                           vtmask, scmask);
    };
    auto g64 = [&](const ushortT* Bw, const ushortT* A, float* oF, ushortT* oB,
                   int M, int Ncc, int Kc, const float* bias, const float* resf,
                   const ushortT* resb, const float* alp, int relu) {
        hipLaunchKernelGGL(gemm64, dim3(Ncc / 128, M / 64), tb, 0, stream,
                           Bw, A, oF, oB, M, Ncc, Kc, bias, resf, resb, alp, relu);
    };
    auto uni = [&](const ushortT* w) { PtrsB b; for (int i = 0; i < 12; ++i) b.p[i] = w; return b; };
    auto d1 = [&](ushortT* d) { PtrsD dd = {}; dd.p[0] = d; return dd; };

    // 2. HA projections: ONE fused GEMM, N=3072 (Q/QA/QB/QD pre-scaled, scmask=57)
    {
        PtrsB b;
        b.p[0] = b.p[1] = wbHead + 0 * WS;
        b.p[2] = b.p[3] = wbHead + 1 * WS;
        b.p[4] = b.p[5] = wbHead + 2 * WS;
        b.p[6] = wbHead + 4 * WS; b.p[7] = wbHead + 8 * WS;
        b.p[8] = wbHead + 5 * WS; b.p[9] = wbHead + 7 * WS;
        b.p[10] = wbHead + 3 * WS; b.p[11] = wbHead + 6 * WS;
        PtrsD d; d.p[0] = bufQ; d.p[1] = bufK; d.p[2] = bufVt;
        d.p[3] = bufQA; d.p[4] = bufQB; d.p[5] = bufQD;
        gemm(b, d, xbf, nullptr, TOK, 3072, 512, nullptr, nullptr, nullptr, 0, 6, 4, 57);
    }

    // 3. HA attention
    hipLaunchKernelGGL(diag_dot_bb, dim3(Bb * Nn * Hh / 256), tb, 0, stream, bufQD, bufK, Sd);
    hipLaunchKernelGGL((attn10<1>), dim3(Nn / 64, Hh, Bb), tb, 0, stream,
                       bufQ, bufK, bufVt, bufQA, bufQB, Sd, bufHA);

    // 4. comb3 + FF3 (bf16 residual stream)
    g64(wbComb + 2 * WS, bufHA, nullptr, curb, TOK, 512, 512, comb3_b, x, nullptr, alpha3, 0);
    gemm(uni(wbFf1 + 2 * WF), d1(hidden), curb, nullptr, TOK, 2048, 512, ff3_b1, nullptr, nullptr, 1, 0, 0, 0);
    g64(wbFf2 + 2 * WF, hidden, nullptr, curb, TOK, 512, 2048, ff3_b2, nullptr, curb, ffa3, 0);

    // 5. MHA1
    {
        PtrsB b;
        b.p[0] = b.p[1] = wbMha + 0 * WS;
        b.p[2] = b.p[3] = wbMha + 1 * WS;
        b.p[4] = b.p[5] = wbMha + 2 * WS;
        PtrsD d = {}; d.p[0] = bufQ; d.p[1] = bufK; d.p[2] = bufVt;
        gemm(b, d, curb, nullptr, TOK, 1536, 512, nullptr, nullptr, nullptr, 0, 3, 4, 1);
    }
    hipLaunchKernelGGL((attn10<0>), dim3(Nn / 64, Hh, Bb), tb, 0, stream,
                       bufQ, bufK, bufVt, nullptr, nullptr, nullptr, bufHA);
    g64(wbComb + 0 * WS, bufHA, nullptr, curb, TOK, 512, 512, comb_b, nullptr, curb, alpha1, 0);
    gemm(uni(wbFf1 + 0 * WF), d1(hidden), curb, nullptr, TOK, 2048, 512, ff1_b1, nullptr, nullptr, 1, 0, 0, 0);
    g64(wbFf2 + 0 * WF, hidden, nullptr, curb, TOK, 512, 2048, ff1_b2, nullptr, curb, ffa1, 0);

    // 6. MHA2
    {
        PtrsB b;
        b.p[0] = wbMha + 3 * WS; b.p[1] = wbMha + 4 * WS;
        b.p[2] = b.p[3] = wbMha + 5 * WS;
        b.p[4] = b.p[5] = wbMha + 6 * WS;
        PtrsD d = {}; d.p[0] = bufQ; d.p[1] = bufK; d.p[2] = bufVt;
        gemm(b, d, curb, nullptr, TOK, 1536, 512, nullptr, nullptr, nullptr, 0, 3, 4, 1);
    }
    hipLaunchKernelGGL((attn10<0>), dim3(Nn / 64, Hh, Bb), tb, 0, stream,
                       bufQ, bufK, bufVt, nullptr, nullptr, nullptr, bufHA);
    g64(wbComb + 1 * WS, bufHA, nullptr, curb, TOK, 512, 512, comb2_b, nullptr, curb, alpha2, 0);
    gemm(uni(wbFf1 + 1 * WF), d1(hidden), curb, nullptr, TOK, 2048, 512, ff2_b1, nullptr, nullptr, 1, 0, 0, 0);
    // final: write f32 d_out
    g64(wbFf2 + 1 * WF, hidden, cur, nullptr, TOK, 512, 2048, ff2_b2, nullptr, curb, ffa2, 0);
}

// Round 19
// 426.450 us; speedup vs baseline: 1.0336x; 1.0336x over previous
//
#include <hip/hip_runtime.h>
#include <math.h>

#define Hh 8
#define Bb 16
#define Nn 512
#define Dd 512
#define VDd 64
#define NPICKk 256
#define NORMF 0.125f
#define SCL2 0.1803368801f   /* NORMF * log2(e) */

typedef unsigned short ushortT;
typedef __bf16 bf16x8 __attribute__((ext_vector_type(8)));
typedef float f32x4 __attribute__((ext_vector_type(4)));

struct PtrsB { const ushortT* p[12]; };
struct PtrsD { ushortT* p[6]; };
struct Ptrs9 { const float* p[9]; };
struct Ptrs10 { const float* p[10]; };
struct Ptrs6 { const float* p[6]; };

__device__ inline ushortT f2bf(float f) {
    __bf16 h = (__bf16)f;
    union { __bf16 h; ushortT u; } v; v.h = h;
    return v.u;
}
__device__ inline float bf2f(ushortT u) {
    union { unsigned int u; float f; } v; v.u = ((unsigned int)u) << 16;
    return v.f;
}
__device__ inline float exp2fast(float x) {
#if __has_builtin(__builtin_amdgcn_exp2f)
    return __builtin_amdgcn_exp2f(x);
#else
    return exp2f(x);
#endif
}
__device__ inline void gload16(const void* gptr, void* ldsptr) {
    auto g = reinterpret_cast<const __attribute__((address_space(1))) unsigned int*>(
        reinterpret_cast<uintptr_t>(gptr));
    auto l = reinterpret_cast<__attribute__((address_space(3))) unsigned int*>(
        reinterpret_cast<uintptr_t>(ldsptr));
    __builtin_amdgcn_global_load_lds(g, l, 16, 0, 0);
}

#define LIX(r, g) (((r) << 6) + ((((g) ^ ((r) & 7))) << 3))

// ---------- fp32 -> bf16 elementwise ----------
__global__ __launch_bounds__(256) void castx(const float* __restrict__ in,
                                             ushortT* __restrict__ out) {
    int i = blockIdx.x * 256 + threadIdx.x;
    float4 v = *(const float4*)&in[(size_t)i * 4];
    ushort4 o; o.x = f2bf(v.x); o.y = f2bf(v.y); o.z = f2bf(v.z); o.w = f2bf(v.w);
    *(ushort4*)&out[(size_t)i * 4] = o;
}

// ---------- transpose+cast body ----------
__device__ inline void tbody(const float* __restrict__ in, ushortT* __restrict__ out,
                             int in_ld, int out_ld, int r0, int c0) {
    __shared__ float T[64][65];
    int tr = threadIdx.x >> 4, tc4 = (threadIdx.x & 15) * 4;
#pragma unroll
    for (int p = 0; p < 4; ++p) {
        float4 v = *(const float4*)&in[(size_t)(r0 + tr + p * 16) * in_ld + c0 + tc4];
        T[tr + p * 16][tc4 + 0] = v.x; T[tr + p * 16][tc4 + 1] = v.y;
        T[tr + p * 16][tc4 + 2] = v.z; T[tr + p * 16][tc4 + 3] = v.w;
    }
    __syncthreads();
#pragma unroll
    for (int p = 0; p < 4; ++p) {
        int orow = c0 + tr + p * 16;
        int ocol = r0 + tc4;
        ushort4 o;
        o.x = f2bf(T[tc4 + 0][tr + p * 16]);
        o.y = f2bf(T[tc4 + 1][tr + p * 16]);
        o.z = f2bf(T[tc4 + 2][tr + p * 16]);
        o.w = f2bf(T[tc4 + 3][tr + p * 16]);
        *(ushort4*)&out[(size_t)orow * out_ld + ocol] = o;
    }
}

__global__ __launch_bounds__(256) void thead(Ptrs9 s, ushortT* __restrict__ dst) {
    int w = blockIdx.z >> 3, h = blockIdx.z & 7;
    tbody(s.p[w] + (size_t)h * 512 * 64,
          dst + (size_t)w * 262144 + (size_t)h * 64 * 512,
          64, 512, blockIdx.y * 64, 0);
}
__global__ __launch_bounds__(256) void tsq(Ptrs10 s, ushortT* __restrict__ dst) {
    tbody(s.p[blockIdx.z], dst + (size_t)blockIdx.z * 262144,
          512, 512, blockIdx.y * 64, blockIdx.x * 64);
}
__global__ __launch_bounds__(256) void tff(Ptrs6 s, ushortT* __restrict__ dst) {
    int z = blockIdx.z;
    if (z < 3) { if (blockIdx.y >= 8 || blockIdx.x >= 32) return; }
    else       { if (blockIdx.y >= 32 || blockIdx.x >= 8) return; }
    int in_ld = (z < 3) ? 2048 : 512;
    int out_ld = (z < 3) ? 512 : 2048;
    tbody(s.p[z], dst + (size_t)z * 1048576, in_ld, out_ld,
          blockIdx.y * 64, blockIdx.x * 64);
}

// ---------- 128x128 bf16 MFMA GEMM, BK=64 counted-vmcnt double-buffer + T5 ----------
__global__ __launch_bounds__(256) void gemm_bf(
    PtrsB Bp, PtrsD Db, const ushortT* __restrict__ A, float* __restrict__ outF,
    int M, int N, int K, const float* __restrict__ bias,
    const float* __restrict__ res, const float* __restrict__ alpha,
    int do_relu, int nroute, int vtmask, int scmask)
{
    __shared__ __align__(16) ushortT As[2][128 * 64];
    __shared__ __align__(16) ushortT Bs[2][128 * 64];
    const int tid = threadIdx.x;
    const int wid = tid >> 6, lane = tid & 63;
    const int wm = wid >> 1, wn = wid & 1;
    const int l15 = lane & 15, l4 = lane >> 4;

    int bid = blockIdx.y * gridDim.x + blockIdx.x;
    int nwg = gridDim.x * gridDim.y;
    int q = nwg >> 3;
    int swz = (bid & 7) * q + (bid >> 3);
    int bx = swz % gridDim.x, by = swz / gridDim.x;

    const int r0 = by * 128, c0 = bx * 128;
    const int half = ((r0 & (Nn - 1)) >= NPICKk) ? 1 : 0;
    const ushortT* Bt = Bp.p[((c0 >> 9) << 1) | half];
    const int cB = nroute ? (c0 & 511) : c0;

    const ushortT* aSrc[4];
    const ushortT* bSrc[4];
    int offv[4];
#pragma unroll
    for (int i = 0; i < 4; ++i) {
        int off = wid * 4096 + i * 1024 + lane * 16;
        int row = off >> 7;
        int sg = ((off >> 4) & 7) ^ (row & 7);
        aSrc[i] = A + (size_t)(r0 + row) * K + sg * 8;
        bSrc[i] = Bt + (size_t)(cB + row) * K + sg * 8;
        offv[i] = off;
    }

    const int nkt = K >> 6;
#pragma unroll
    for (int i = 0; i < 4; ++i) {
        gload16(aSrc[i], (char*)As[0] + offv[i]);
        gload16(bSrc[i], (char*)Bs[0] + offv[i]);
    }
#pragma unroll
    for (int i = 0; i < 4; ++i) {
        gload16(aSrc[i] + 64, (char*)As[1] + offv[i]);
        gload16(bSrc[i] + 64, (char*)Bs[1] + offv[i]);
    }

    f32x4 acc[4][4] = {};

    for (int t = 0; t < nkt; ++t) {
        const int cur = t & 1;
        if (t == nkt - 1) asm volatile("s_waitcnt vmcnt(0)" ::: "memory");
        else              asm volatile("s_waitcnt vmcnt(8)" ::: "memory");
        __builtin_amdgcn_s_barrier();
        __builtin_amdgcn_sched_barrier(0);
        const ushortT* Ac = As[cur];
        const ushortT* Bc = Bs[cur];
        __builtin_amdgcn_s_setprio(1);
#pragma unroll
        for (int kk = 0; kk < 2; ++kk) {
            int g0 = kk * 4 + l4;
            bf16x8 af[4], bfv[4];
#pragma unroll
            for (int mi = 0; mi < 4; ++mi)
                af[mi] = *(const bf16x8*)&Ac[LIX(wm * 64 + mi * 16 + l15, g0)];
#pragma unroll
            for (int ni = 0; ni < 4; ++ni)
                bfv[ni] = *(const bf16x8*)&Bc[LIX(wn * 64 + ni * 16 + l15, g0)];
#pragma unroll
            for (int mi = 0; mi < 4; ++mi)
#pragma unroll
                for (int ni = 0; ni < 4; ++ni)
                    acc[mi][ni] = __builtin_amdgcn_mfma_f32_16x16x32_bf16(
                        bfv[ni], af[mi], acc[mi][ni], 0, 0, 0);   // C^T fragment
        }
        __builtin_amdgcn_s_setprio(0);
        __builtin_amdgcn_s_barrier();
        asm volatile("" ::: "memory");
        if (t + 2 < nkt) {
            int kt2 = (t + 2) << 6;
#pragma unroll
            for (int i = 0; i < 4; ++i) {
                gload16(aSrc[i] + kt2, (char*)As[cur] + offv[i]);
                gload16(bSrc[i] + kt2, (char*)Bs[cur] + offv[i]);
            }
        }
    }

    if (nroute) {
#pragma unroll
        for (int mi = 0; mi < 4; ++mi) {
            int row = r0 + wm * 64 + mi * 16 + l15;
#pragma unroll
            for (int ni = 0; ni < 4; ++ni) {
                int col = c0 + wn * 64 + ni * 16 + l4 * 4;
                int range = col >> 9, cc = col & 511;
                ushortT* d = Db.p[range];
                f32x4 a = acc[mi][ni];
                if ((scmask >> range) & 1) {
                    a[0] *= SCL2; a[1] *= SCL2; a[2] *= SCL2; a[3] *= SCL2;
                }
                if ((vtmask >> range) & 1) {
                    size_t vb = ((size_t)(row >> 9) * Hh + (cc >> 6)) * 64 + (cc & 63);
                    int tok = row & 511;
#pragma unroll
                    for (int r = 0; r < 4; ++r)
                        d[((vb + r) << 9) + tok] = f2bf(a[r]);
                } else {
                    ushort4 o;
                    o.x = f2bf(a[0]); o.y = f2bf(a[1]);
                    o.z = f2bf(a[2]); o.w = f2bf(a[3]);
                    *(ushort4*)&d[((size_t)row << 9) + cc] = o;
                }
            }
        }
    } else {
        const float alp = alpha ? alpha[0] : 1.0f;
        ushortT* outB = Db.p[0];
#pragma unroll
        for (int mi = 0; mi < 4; ++mi) {
            int row = r0 + wm * 64 + mi * 16 + l15;
#pragma unroll
            for (int ni = 0; ni < 4; ++ni) {
                int colb = c0 + wn * 64 + ni * 16 + l4 * 4;
                f32x4 a = acc[mi][ni];
                if (bias) {
                    float4 b4 = *(const float4*)&bias[colb];
                    a[0] += b4.x; a[1] += b4.y; a[2] += b4.z; a[3] += b4.w;
                }
                if (do_relu) {
#pragma unroll
                    for (int r = 0; r < 4; ++r) a[r] = fmaxf(a[r], 0.f);
                }
#pragma unroll
                for (int r = 0; r < 4; ++r) a[r] *= alp;
                size_t idx = (size_t)row * N + colb;
                if (res) {
                    float4 r4 = *(const float4*)&res[idx];
                    a[0] += r4.x; a[1] += r4.y; a[2] += r4.z; a[3] += r4.w;
                }
                if (outF)
                    *(float4*)&outF[idx] = make_float4(a[0], a[1], a[2], a[3]);
                if (outB) {
                    ushort4 o;
                    o.x = f2bf(a[0]); o.y = f2bf(a[1]);
                    o.z = f2bf(a[2]); o.w = f2bf(a[3]);
                    *(ushort4*)&outB[idx] = o;
                }
            }
        }
    }
}

// ---------- 64x128 bf16 MFMA GEMM, T4 double-buffer + T5; res f32/bf16 ----------
__global__ __launch_bounds__(256) void gemm64(
    const ushortT* __restrict__ Bw, const ushortT* __restrict__ A,
    float* __restrict__ outF, ushortT* __restrict__ outB,
    int M, int N, int K, const float* __restrict__ bias,
    const float* __restrict__ resf, const ushortT* __restrict__ resb,
    const float* __restrict__ alpha, int do_relu)
{
    __shared__ __align__(16) ushortT As[2][64 * 64];    // 16 KB
    __shared__ __align__(16) ushortT Bs[2][128 * 64];   // 32 KB
    const int tid = threadIdx.x;
    const int wid = tid >> 6, lane = tid & 63;
    const int wm = wid >> 1, wn = wid & 1;
    const int l15 = lane & 15, l4 = lane >> 4;

    int bid = blockIdx.y * gridDim.x + blockIdx.x;
    int nwg = gridDim.x * gridDim.y;
    int q = nwg >> 3;
    int swz = (bid & 7) * q + (bid >> 3);
    int bx = swz % gridDim.x, by = swz / gridDim.x;
    const int r0 = by * 64, c0 = bx * 128;

    const ushortT* aSrc[2];
    int offA[2];
#pragma unroll
    for (int i = 0; i < 2; ++i) {
        int off = wid * 2048 + i * 1024 + lane * 16;
        int row = off >> 7;
        int sg = ((off >> 4) & 7) ^ (row & 7);
        aSrc[i] = A + (size_t)(r0 + row) * K + sg * 8;
        offA[i] = off;
    }
    const ushortT* bSrc[4];
    int offB[4];
#pragma unroll
    for (int i = 0; i < 4; ++i) {
        int off = wid * 4096 + i * 1024 + lane * 16;
        int row = off >> 7;
        int sg = ((off >> 4) & 7) ^ (row & 7);
        bSrc[i] = Bw + (size_t)(c0 + row) * K + sg * 8;
        offB[i] = off;
    }

    const int nkt = K >> 6;
#pragma unroll
    for (int i = 0; i < 2; ++i) gload16(aSrc[i], (char*)As[0] + offA[i]);
#pragma unroll
    for (int i = 0; i < 4; ++i) gload16(bSrc[i], (char*)Bs[0] + offB[i]);
#pragma unroll
    for (int i = 0; i < 2; ++i) gload16(aSrc[i] + 64, (char*)As[1] + offA[i]);
#pragma unroll
    for (int i = 0; i < 4; ++i) gload16(bSrc[i] + 64, (char*)Bs[1] + offB[i]);

    f32x4 acc[2][4] = {};

    for (int t = 0; t < nkt; ++t) {
        const int cur = t & 1;
        if (t == nkt - 1) asm volatile("s_waitcnt vmcnt(0)" ::: "memory");
        else              asm volatile("s_waitcnt vmcnt(6)" ::: "memory");
        __builtin_amdgcn_s_barrier();
        __builtin_amdgcn_sched_barrier(0);
        const ushortT* Ac = As[cur];
        const ushortT* Bc = Bs[cur];
        __builtin_amdgcn_s_setprio(1);
#pragma unroll
        for (int kk = 0; kk < 2; ++kk) {
            int g0 = kk * 4 + l4;
            bf16x8 af[2], bfv[4];
#pragma unroll
            for (int mi = 0; mi < 2; ++mi)
                af[mi] = *(const bf16x8*)&Ac[LIX(wm * 32 + mi * 16 + l15, g0)];
#pragma unroll
            for (int ni = 0; ni < 4; ++ni)
                bfv[ni] = *(const bf16x8*)&Bc[LIX(wn * 64 + ni * 16 + l15, g0)];
#pragma unroll
            for (int mi = 0; mi < 2; ++mi)
#pragma unroll
                for (int ni = 0; ni < 4; ++ni)
                    acc[mi][ni] = __builtin_amdgcn_mfma_f32_16x16x32_bf16(
                        bfv[ni], af[mi], acc[mi][ni], 0, 0, 0);
        }
        __builtin_amdgcn_s_setprio(0);
        __builtin_amdgcn_s_barrier();
        asm volatile("" ::: "memory");
        if (t + 2 < nkt) {
            int kt2 = (t + 2) << 6;
#pragma unroll
            for (int i = 0; i < 2; ++i) gload16(aSrc[i] + kt2, (char*)As[cur] + offA[i]);
#pragma unroll
            for (int i = 0; i < 4; ++i) gload16(bSrc[i] + kt2, (char*)Bs[cur] + offB[i]);
        }
    }

    const float alp = alpha ? alpha[0] : 1.0f;
#pragma unroll
    for (int mi = 0; mi < 2; ++mi) {
        int row = r0 + wm * 32 + mi * 16 + l15;
#pragma unroll
        for (int ni = 0; ni < 4; ++ni) {
            int colb = c0 + wn * 64 + ni * 16 + l4 * 4;
            f32x4 a = acc[mi][ni];
            if (bias) {
                float4 b4 = *(const float4*)&bias[colb];
                a[0] += b4.x; a[1] += b4.y; a[2] += b4.z; a[3] += b4.w;
            }
            if (do_relu) {
#pragma unroll
                for (int r = 0; r < 4; ++r) a[r] = fmaxf(a[r], 0.f);
            }
#pragma unroll
            for (int r = 0; r < 4; ++r) a[r] *= alp;
            size_t idx = (size_t)row * N + colb;
            if (resf) {
                float4 r4 = *(const float4*)&resf[idx];
                a[0] += r4.x; a[1] += r4.y; a[2] += r4.z; a[3] += r4.w;
            }
            if (resb) {
                ushort4 r4 = *(const ushort4*)&resb[idx];
                a[0] += bf2f(r4.x); a[1] += bf2f(r4.y);
                a[2] += bf2f(r4.z); a[3] += bf2f(r4.w);
            }
            if (outF)
                *(float4*)&outF[idx] = make_float4(a[0], a[1], a[2], a[3]);
            if (outB) {
                ushort4 o;
                o.x = f2bf(a[0]); o.y = f2bf(a[1]);
                o.z = f2bf(a[2]); o.w = f2bf(a[3]);
                *(ushort4*)&outB[idx] = o;
            }
        }
    }
}

// ---------- HA diagonal scores (QD pre-scaled by NORM*log2e) ----------
__global__ __launch_bounds__(256) void diag_dot_bb(const ushortT* __restrict__ QD,
                                                   const ushortT* __restrict__ K,
                                                   float* __restrict__ Sdg) {
    int i = blockIdx.x * 256 + threadIdx.x;
    int h = i & 7, n = (i >> 3) & 511, b = i >> 12;
    int dix = (n < NPICKk) ? n + NPICKk : n - NPICKk;
    const ushortT* q = QD + (((size_t)(b * Nn + n) * Hh + h) << 6);
    const ushortT* k = K + (((size_t)(b * Nn + dix) * Hh + h) << 6);
    float s = 0.f;
#pragma unroll
    for (int d = 0; d < 64; d += 4) {
        ushort4 a = *(const ushort4*)(q + d);
        ushort4 c = *(const ushort4*)(k + d);
        s += bf2f(a.x) * bf2f(c.x) + bf2f(a.y) * bf2f(c.y)
           + bf2f(a.z) * bf2f(c.z) + bf2f(a.w) * bf2f(c.w);
    }
    Sdg[i] = s;
}

// ---------- flash attention: T14 reg-staged double-buffered K/V, lazy max, deferred L ----------
template <int HA>
__global__ __launch_bounds__(256) void attn10(
    const ushortT* __restrict__ Qm, const ushortT* __restrict__ Km,
    const ushortT* __restrict__ Vtm, const ushortT* __restrict__ QAm,
    const ushortT* __restrict__ QBm, const float* __restrict__ Sdg,
    ushortT* __restrict__ Out)
{
    __shared__ __align__(16) ushortT Ks[64 * 64];
    __shared__ __align__(16) ushortT Vs[64 * 64];
    __shared__ __align__(16) ushortT Pw[4][16 * 64];
    __shared__ float sdl[64];

    const int tid = threadIdx.x, wid = tid >> 6, lane = tid & 63;
    const int l15 = lane & 15, l4 = lane >> 4;

    const int p = blockIdx.x + (blockIdx.y << 3) + (blockIdx.z << 6);
    const int n0 = (((p >> 3) & 7)) << 6;
    const int g8 = (p & 7) | ((p >> 6) << 3);
    const int h = g8 & 7, b = g8 >> 3;
    const int bh = b * Hh + h;

    const size_t qrow = (((size_t)(b * Nn + n0 + wid * 16 + l15) * Hh + h) << 6);
    bf16x8 qf[2], xaf[2], xbf[2];
#pragma unroll
    for (int kk = 0; kk < 2; ++kk) {
        int g0 = kk * 4 + l4;
        qf[kk] = *(const bf16x8*)&Qm[qrow + g0 * 8];
        if (HA) {
            xaf[kk] = *(const bf16x8*)&QAm[qrow + g0 * 8];
            xbf[kk] = *(const bf16x8*)&QBm[qrow + g0 * 8];
        }
    }
    if (HA && tid < 64) sdl[tid] = Sdg[((size_t)(b * Nn + n0 + tid)) * Hh + h];
    const int td = (n0 < NPICKk) ? ((n0 + NPICKk) >> 6) : ((n0 - NPICKk) >> 6);

    const ushortT* kSrc[2]; ushortT* kDst[2];
    const ushortT* vSrc[2]; ushortT* vDst[2];
#pragma unroll
    for (int i = 0; i < 2; ++i) {
        int off = wid * 2048 + i * 1024 + lane * 16;
        int row = off >> 7, sg = ((off >> 4) & 7) ^ (row & 7);
        kSrc[i] = Km + (((size_t)(b * Nn + row) * Hh + h) << 6) + sg * 8;
        kDst[i] = (ushortT*)((char*)Ks + off);
        vSrc[i] = Vtm + (((size_t)(bh * 64 + row)) << 9) + sg * 8;
        vDst[i] = (ushortT*)((char*)Vs + off);
    }

    float M[4], Lp[4];
    f32x4 Oa[4] = {};
#pragma unroll
    for (int r = 0; r < 4; ++r) { M[r] = -INFINITY; Lp[r] = 0.f; }

    bf16x8 krbuf[2][2], vrbuf[2][2];
#pragma unroll
    for (int i = 0; i < 2; ++i) {
        krbuf[0][i] = *(const bf16x8*)kSrc[i];
        vrbuf[0][i] = *(const bf16x8*)vSrc[i];
    }

#pragma unroll
    for (int t = 0; t < 8; ++t) {
        const int cur = t & 1, nxt = cur ^ 1;
        __builtin_amdgcn_s_barrier();
#pragma unroll
        for (int i = 0; i < 2; ++i) {
            *(bf16x8*)kDst[i] = krbuf[cur][i];
            *(bf16x8*)vDst[i] = vrbuf[cur][i];
        }
        if (t < 7) {
#pragma unroll
            for (int i = 0; i < 2; ++i) {
                krbuf[nxt][i] = *(const bf16x8*)(kSrc[i] + (size_t)(t + 1) * (64 * Hh * VDd));
                vrbuf[nxt][i] = *(const bf16x8*)(vSrc[i] + (t + 1) * 64);
            }
        }
        asm volatile("s_waitcnt lgkmcnt(0)" ::: "memory");
        __builtin_amdgcn_s_barrier();
        __builtin_amdgcn_sched_barrier(0);

        __builtin_amdgcn_s_setprio(1);
        f32x4 s1[4] = {}, sX[4] = {};
#pragma unroll
        for (int kk = 0; kk < 2; ++kk) {
            bf16x8 aq = qf[kk];
            bf16x8 ax;
            if (HA) ax = (t >= 4) ? xbf[kk] : xaf[kk];
#pragma unroll
            for (int ni = 0; ni < 4; ++ni) {
                bf16x8 bk = *(const bf16x8*)&Ks[LIX(ni * 16 + l15, kk * 4 + l4)];
                s1[ni] = __builtin_amdgcn_mfma_f32_16x16x32_bf16(aq, bk, s1[ni], 0, 0, 0);
                if (HA)
                    sX[ni] = __builtin_amdgcn_mfma_f32_16x16x32_bf16(ax, bk, sX[ni], 0, 0, 0);
            }
        }
        __builtin_amdgcn_s_setprio(0);

        const bool dt = HA && (t == td);

        float mloc[4];
        bool grow = false;
#pragma unroll
        for (int r = 0; r < 4; ++r) {
            int rw = wid * 16 + l4 * 4 + r;
            float m = s1[0][r];
#pragma unroll
            for (int ni = 1; ni < 4; ++ni) m = fmaxf(m, s1[ni][r]);
            if (HA) {
#pragma unroll
                for (int ni = 0; ni < 4; ++ni) m = fmaxf(m, sX[ni][r]);
            }
            if (dt && l15 == l4 * 4 + r) m = fmaxf(m, sdl[rw]);
            mloc[r] = m;
            grow = grow || (m > M[r] + 8.f);
        }
        if (__any(grow)) {
#pragma unroll
            for (int r = 0; r < 4; ++r) {
                float m = mloc[r];
#pragma unroll
                for (int o = 8; o >= 1; o >>= 1) m = fmaxf(m, __shfl_xor(m, o, 16));
                float mn = fmaxf(M[r], m);
                float sc = exp2fast(M[r] - mn);
                M[r] = mn; Lp[r] *= sc;
#pragma unroll
                for (int ni = 0; ni < 4; ++ni) Oa[ni][r] *= sc;
            }
        }

#pragma unroll
        for (int r = 0; r < 4; ++r) {
            int rw = wid * 16 + l4 * 4 + r;
            float rs = 0.f;
#pragma unroll
            for (int ni = 0; ni < 4; ++ni) {
                float pv = exp2fast(s1[ni][r] - M[r]);
                if (HA) pv += exp2fast(sX[ni][r] - M[r]);
                if (dt && ni == wid && l15 == l4 * 4 + r) pv += exp2fast(sdl[rw] - M[r]);
                s1[ni][r] = pv;
                rs += pv;
            }
            Lp[r] += rs;
        }

#pragma unroll
        for (int ni = 0; ni < 4; ++ni)
#pragma unroll
            for (int r = 0; r < 4; ++r) {
                int prow = l4 * 4 + r;
                int col = ni * 16 + l15;
                Pw[wid][(prow << 6) + ((((col >> 3) ^ (prow & 7))) << 3) + (col & 7)] =
                    f2bf(s1[ni][r]);
            }

        __builtin_amdgcn_s_setprio(1);
#pragma unroll
        for (int kk = 0; kk < 2; ++kk) {
            int g0 = kk * 4 + l4;
            bf16x8 ap = *(const bf16x8*)&Pw[wid][LIX(l15, g0)];
#pragma unroll
            for (int ni = 0; ni < 4; ++ni) {
                bf16x8 bv = *(const bf16x8*)&Vs[LIX(ni * 16 + l15, g0)];
                Oa[ni] = __builtin_amdgcn_mfma_f32_16x16x32_bf16(ap, bv, Oa[ni], 0, 0, 0);
            }
        }
        __builtin_amdgcn_s_setprio(0);
    }

#pragma unroll
    for (int r = 0; r < 4; ++r) {
        float l = Lp[r];
#pragma unroll
        for (int o = 8; o >= 1; o >>= 1) l += __shfl_xor(l, o, 16);
        float inv = 1.0f / l;
        size_t obase = (((size_t)(b * Nn + n0 + wid * 16 + l4 * 4 + r) * Hh + h) << 6);
#pragma unroll
        for (int ni = 0; ni < 4; ++ni)
            Out[obase + ni * 16 + l15] = f2bf(Oa[ni][r] * inv);
    }
}

extern "C" void kernel_launch(void* const* d_in, const int* in_sizes, int n_in,
                              void* d_out, int out_size, void* d_ws, size_t ws_size,
                              hipStream_t stream)
{
    const float* x = (const float*)d_in[0];

    int dictOrder = (in_sizes[18] != 512);
    const float* comb_w  = (const float*)d_in[17];
    const float* comb2_w = (const float*)d_in[dictOrder ? 18 : 19];
    const float* comb3_w = (const float*)d_in[dictOrder ? 19 : 21];
    const float* comb_b  = (const float*)d_in[dictOrder ? 20 : 18];
    const float* comb2_b = (const float*)d_in[dictOrder ? 21 : 20];
    const float* comb3_b = (const float*)d_in[22];
    const float* alpha1 = (const float*)d_in[23];
    const float* alpha2 = (const float*)d_in[24];
    const float* alpha3 = (const float*)d_in[25];
    const float* ff1_w1 = (const float*)d_in[26];
    const float* ff1_b1 = (const float*)d_in[27];
    const float* ff1_w2 = (const float*)d_in[28];
    const float* ff1_b2 = (const float*)d_in[29];
    const float* ffa1   = (const float*)d_in[30];
    const float* ff2_w1 = (const float*)d_in[31];
    const float* ff2_b1 = (const float*)d_in[32];
    const float* ff2_w2 = (const float*)d_in[33];
    const float* ff2_b2 = (const float*)d_in[34];
    const float* ffa2   = (const float*)d_in[35];
    const float* ff3_w1 = (const float*)d_in[36];
    const float* ff3_b1 = (const float*)d_in[37];
    const float* ff3_w2 = (const float*)d_in[38];
    const float* ff3_b2 = (const float*)d_in[39];
    const float* ffa3   = (const float*)d_in[40];

    // ---- workspace layout (bytes) ----
    char* W = (char*)d_ws;
    ushortT* wbHead = (ushortT*)(W + 0);
    ushortT* wbMha  = (ushortT*)(W + 4718592);
    ushortT* wbComb = (ushortT*)(W + 8388608);
    ushortT* wbFf1  = (ushortT*)(W + 9961472);
    ushortT* wbFf2  = (ushortT*)(W + 16252928);
    ushortT* xbf    = (ushortT*)(W + 22544384);
    float*   Sd     = (float*)  (W + 30932992);
    ushortT* bufQ   = (ushortT*)(W + 31195136);
    ushortT* bufK   = (ushortT*)(W + 39583744);
    ushortT* bufVt  = (ushortT*)(W + 47972352);
    ushortT* bufQA  = (ushortT*)(W + 56360960);
    ushortT* bufQB  = (ushortT*)(W + 64749568);
    ushortT* bufQD  = (ushortT*)(W + 73138176);
    ushortT* hidden = (ushortT*)(W + 81526784);
    ushortT* curb   = (ushortT*)(W + 115081216);
    ushortT* bufHA  = xbf;
    float*   cur    = (float*)d_out;

    dim3 tb(256);
    const int TOK = Bb * Nn;  // 8192
    const size_t WS = 512 * 512;
    const size_t WF = 2048 * 512;

    // 1. casts / transposes (batched)
    hipLaunchKernelGGL(castx, dim3(TOK * 512 / 1024), tb, 0, stream, x, xbf);
    {
        Ptrs9 s; for (int i = 0; i < 9; ++i) s.p[i] = (const float*)d_in[1 + i];
        hipLaunchKernelGGL(thead, dim3(1, 8, 72), tb, 0, stream, s, wbHead);
    }
    {
        Ptrs10 s;
        for (int i = 0; i < 7; ++i) s.p[i] = (const float*)d_in[10 + i];
        s.p[7] = comb_w; s.p[8] = comb2_w; s.p[9] = comb3_w;
        hipLaunchKernelGGL(tsq, dim3(8, 8, 10), tb, 0, stream, s, wbMha);
    }
    {
        Ptrs6 s;
        s.p[0] = ff1_w1; s.p[1] = ff2_w1; s.p[2] = ff3_w1;
        s.p[3] = ff1_w2; s.p[4] = ff2_w2; s.p[5] = ff3_w2;
        hipLaunchKernelGGL(tff, dim3(32, 32, 6), tb, 0, stream, s, wbFf1);
    }

    auto gemm = [&](PtrsB Bp, PtrsD Db, const ushortT* A, float* oF,
                    int M, int Ncc, int Kc, const float* bias, const float* res,
                    const float* alp, int relu, int nroute, int vtmask, int scmask) {
        hipLaunchKernelGGL(gemm_bf, dim3(Ncc / 128, M / 128), tb, 0, stream,
                           Bp, Db, A, oF, M, Ncc, Kc, bias, res, alp, relu, nroute,
                           vtmask, scmask);
    };
    auto g64 = [&](const ushortT* Bw, const ushortT* A, float* oF, ushortT* oB,
                   int M, int Ncc, int Kc, const float* bias, const float* resf,
                   const ushortT* resb, const float* alp, int relu) {
        hipLaunchKernelGGL(gemm64, dim3(Ncc / 128, M / 64), tb, 0, stream,
                           Bw, A, oF, oB, M, Ncc, Kc, bias, resf, resb, alp, relu);
    };
    auto uni = [&](const ushortT* w) { PtrsB b; for (int i = 0; i < 12; ++i) b.p[i] = w; return b; };
    auto d1 = [&](ushortT* d) { PtrsD dd = {}; dd.p[0] = d; return dd; };

    // 2. HA projections: ONE fused GEMM, N=3072 (Q/QA/QB/QD pre-scaled, scmask=57)
    {
        PtrsB b;
        b.p[0] = b.p[1] = wbHead + 0 * WS;
        b.p[2] = b.p[3] = wbHead + 1 * WS;
        b.p[4] = b.p[5] = wbHead + 2 * WS;
        b.p[6] = wbHead + 4 * WS; b.p[7] = wbHead + 8 * WS;
        b.p[8] = wbHead + 5 * WS; b.p[9] = wbHead + 7 * WS;
        b.p[10] = wbHead + 3 * WS; b.p[11] = wbHead + 6 * WS;
        PtrsD d; d.p[0] = bufQ; d.p[1] = bufK; d.p[2] = bufVt;
        d.p[3] = bufQA; d.p[4] = bufQB; d.p[5] = bufQD;
        gemm(b, d, xbf, nullptr, TOK, 3072, 512, nullptr, nullptr, nullptr, 0, 6, 4, 57);
    }

    // 3. HA attention
    hipLaunchKernelGGL(diag_dot_bb, dim3(Bb * Nn * Hh / 256), tb, 0, stream, bufQD, bufK, Sd);
    hipLaunchKernelGGL((attn10<1>), dim3(Nn / 64, Hh, Bb), tb, 0, stream,
                       bufQ, bufK, bufVt, bufQA, bufQB, Sd, bufHA);

    // 4. comb3 + FF3 (bf16 residual stream)
    g64(wbComb + 2 * WS, bufHA, nullptr, curb, TOK, 512, 512, comb3_b, x, nullptr, alpha3, 0);
    gemm(uni(wbFf1 + 2 * WF), d1(hidden), curb, nullptr, TOK, 2048, 512, ff3_b1, nullptr, nullptr, 1, 0, 0, 0);
    g64(wbFf2 + 2 * WF, hidden, nullptr, curb, TOK, 512, 2048, ff3_b2, nullptr, curb, ffa3, 0);

    // 5. MHA1
    {
        PtrsB b;
        b.p[0] = b.p[1] = wbMha + 0 * WS;
        b.p[2] = b.p[3] = wbMha + 1 * WS;
        b.p[4] = b.p[5] = wbMha + 2 * WS;
        PtrsD d = {}; d.p[0] = bufQ; d.p[1] = bufK; d.p[2] = bufVt;
        gemm(b, d, curb, nullptr, TOK, 1536, 512, nullptr, nullptr, nullptr, 0, 3, 4, 1);
    }
    hipLaunchKernelGGL((attn10<0>), dim3(Nn / 64, Hh, Bb), tb, 0, stream,
                       bufQ, bufK, bufVt, nullptr, nullptr, nullptr, bufHA);
    g64(wbComb + 0 * WS, bufHA, nullptr, curb, TOK, 512, 512, comb_b, nullptr, curb, alpha1, 0);
    gemm(uni(wbFf1 + 0 * WF), d1(hidden), curb, nullptr, TOK, 2048, 512, ff1_b1, nullptr, nullptr, 1, 0, 0, 0);
    g64(wbFf2 + 0 * WF, hidden, nullptr, curb, TOK, 512, 2048, ff1_b2, nullptr, curb, ffa1, 0);

    // 6. MHA2
    {
        PtrsB b;
        b.p[0] = wbMha + 3 * WS; b.p[1] = wbMha + 4 * WS;
        b.p[2] = b.p[3] = wbMha + 5 * WS;
        b.p[4] = b.p[5] = wbMha + 6 * WS;
        PtrsD d = {}; d.p[0] = bufQ; d.p[1] = bufK; d.p[2] = bufVt;
        gemm(b, d, curb, nullptr, TOK, 1536, 512, nullptr, nullptr, nullptr, 0, 3, 4, 1);
    }
    hipLaunchKernelGGL((attn10<0>), dim3(Nn / 64, Hh, Bb), tb, 0, stream,
                       bufQ, bufK, bufVt, nullptr, nullptr, nullptr, bufHA);
    g64(wbComb + 1 * WS, bufHA, nullptr, curb, TOK, 512, 512, comb2_b, nullptr, curb, alpha2, 0);
    gemm(uni(wbFf1 + 1 * WF), d1(hidden), curb, nullptr, TOK, 2048, 512, ff2_b1, nullptr, nullptr, 1, 0, 0, 0);
    // final: write f32 d_out
    g64(wbFf2 + 1 * WF, hidden, cur, nullptr, TOK, 512, 2048, ff2_b2, nullptr, curb, ffa2, 0);
}

// Round 20
// 413.803 us; speedup vs baseline: 1.0652x; 1.0306x over previous
//
#include <hip/hip_runtime.h>
#include <math.h>

#define Hh 8
#define Bb 16
#define Nn 512
#define Dd 512
#define VDd 64
#define NPICKk 256
#define NORMF 0.125f
#define SCL2 0.1803368801f   /* NORMF * log2(e) */

typedef unsigned short ushortT;
typedef __bf16 bf16x8 __attribute__((ext_vector_type(8)));
typedef float f32x4 __attribute__((ext_vector_type(4)));

struct PtrsB { const ushortT* p[12]; };
struct PtrsD { ushortT* p[6]; };
struct Ptrs9 { const float* p[9]; };
struct Ptrs10 { const float* p[10]; };
struct Ptrs6 { const float* p[6]; };

__device__ inline ushortT f2bf(float f) {
    __bf16 h = (__bf16)f;
    union { __bf16 h; ushortT u; } v; v.h = h;
    return v.u;
}
__device__ inline float bf2f(ushortT u) {
    union { unsigned int u; float f; } v; v.u = ((unsigned int)u) << 16;
    return v.f;
}
__device__ inline float exp2fast(float x) {
#if __has_builtin(__builtin_amdgcn_exp2f)
    return __builtin_amdgcn_exp2f(x);
#else
    return exp2f(x);
#endif
}
__device__ inline void gload16(const void* gptr, void* ldsptr) {
    auto g = reinterpret_cast<const __attribute__((address_space(1))) unsigned int*>(
        reinterpret_cast<uintptr_t>(gptr));
    auto l = reinterpret_cast<__attribute__((address_space(3))) unsigned int*>(
        reinterpret_cast<uintptr_t>(ldsptr));
    __builtin_amdgcn_global_load_lds(g, l, 16, 0, 0);
}

#define LIX(r, g) (((r) << 6) + ((((g) ^ ((r) & 7))) << 3))

// ---------- fp32 -> bf16 elementwise ----------
__global__ __launch_bounds__(256) void castx(const float* __restrict__ in,
                                             ushortT* __restrict__ out) {
    int i = blockIdx.x * 256 + threadIdx.x;
    float4 v = *(const float4*)&in[(size_t)i * 4];
    ushort4 o; o.x = f2bf(v.x); o.y = f2bf(v.y); o.z = f2bf(v.z); o.w = f2bf(v.w);
    *(ushort4*)&out[(size_t)i * 4] = o;
}

// ---------- transpose+cast body ----------
__device__ inline void tbody(const float* __restrict__ in, ushortT* __restrict__ out,
                             int in_ld, int out_ld, int r0, int c0) {
    __shared__ float T[64][65];
    int tr = threadIdx.x >> 4, tc4 = (threadIdx.x & 15) * 4;
#pragma unroll
    for (int p = 0; p < 4; ++p) {
        float4 v = *(const float4*)&in[(size_t)(r0 + tr + p * 16) * in_ld + c0 + tc4];
        T[tr + p * 16][tc4 + 0] = v.x; T[tr + p * 16][tc4 + 1] = v.y;
        T[tr + p * 16][tc4 + 2] = v.z; T[tr + p * 16][tc4 + 3] = v.w;
    }
    __syncthreads();
#pragma unroll
    for (int p = 0; p < 4; ++p) {
        int orow = c0 + tr + p * 16;
        int ocol = r0 + tc4;
        ushort4 o;
        o.x = f2bf(T[tc4 + 0][tr + p * 16]);
        o.y = f2bf(T[tc4 + 1][tr + p * 16]);
        o.z = f2bf(T[tc4 + 2][tr + p * 16]);
        o.w = f2bf(T[tc4 + 3][tr + p * 16]);
        *(ushort4*)&out[(size_t)orow * out_ld + ocol] = o;
    }
}

__global__ __launch_bounds__(256) void thead(Ptrs9 s, ushortT* __restrict__ dst) {
    int w = blockIdx.z >> 3, h = blockIdx.z & 7;
    tbody(s.p[w] + (size_t)h * 512 * 64,
          dst + (size_t)w * 262144 + (size_t)h * 64 * 512,
          64, 512, blockIdx.y * 64, 0);
}
__global__ __launch_bounds__(256) void tsq(Ptrs10 s, ushortT* __restrict__ dst) {
    tbody(s.p[blockIdx.z], dst + (size_t)blockIdx.z * 262144,
          512, 512, blockIdx.y * 64, blockIdx.x * 64);
}
__global__ __launch_bounds__(256) void tff(Ptrs6 s, ushortT* __restrict__ dst) {
    int z = blockIdx.z;
    if (z < 3) { if (blockIdx.y >= 8 || blockIdx.x >= 32) return; }
    else       { if (blockIdx.y >= 32 || blockIdx.x >= 8) return; }
    int in_ld = (z < 3) ? 2048 : 512;
    int out_ld = (z < 3) ? 512 : 2048;
    tbody(s.p[z], dst + (size_t)z * 1048576, in_ld, out_ld,
          blockIdx.y * 64, blockIdx.x * 64);
}

// ---------- 128x128 bf16 MFMA GEMM, BK=64 counted-vmcnt double-buffer + T5 ----------
__global__ __launch_bounds__(256) void gemm_bf(
    PtrsB Bp, PtrsD Db, const ushortT* __restrict__ A, float* __restrict__ outF,
    int M, int N, int K, const float* __restrict__ bias,
    const float* __restrict__ res, const float* __restrict__ alpha,
    int do_relu, int nroute, int vtmask, int scmask)
{
    __shared__ __align__(16) ushortT As[2][128 * 64];
    __shared__ __align__(16) ushortT Bs[2][128 * 64];
    const int tid = threadIdx.x;
    const int wid = tid >> 6, lane = tid & 63;
    const int wm = wid >> 1, wn = wid & 1;
    const int l15 = lane & 15, l4 = lane >> 4;

    int bid = blockIdx.y * gridDim.x + blockIdx.x;
    int nwg = gridDim.x * gridDim.y;
    int q = nwg >> 3;
    int swz = (bid & 7) * q + (bid >> 3);
    int bx = swz % gridDim.x, by = swz / gridDim.x;

    const int r0 = by * 128, c0 = bx * 128;
    const int half = ((r0 & (Nn - 1)) >= NPICKk) ? 1 : 0;
    const ushortT* Bt = Bp.p[((c0 >> 9) << 1) | half];
    const int cB = nroute ? (c0 & 511) : c0;

    const ushortT* aSrc[4];
    const ushortT* bSrc[4];
    int offv[4];
#pragma unroll
    for (int i = 0; i < 4; ++i) {
        int off = wid * 4096 + i * 1024 + lane * 16;
        int row = off >> 7;
        int sg = ((off >> 4) & 7) ^ (row & 7);
        aSrc[i] = A + (size_t)(r0 + row) * K + sg * 8;
        bSrc[i] = Bt + (size_t)(cB + row) * K + sg * 8;
        offv[i] = off;
    }

    const int nkt = K >> 6;
#pragma unroll
    for (int i = 0; i < 4; ++i) {
        gload16(aSrc[i], (char*)As[0] + offv[i]);
        gload16(bSrc[i], (char*)Bs[0] + offv[i]);
    }
#pragma unroll
    for (int i = 0; i < 4; ++i) {
        gload16(aSrc[i] + 64, (char*)As[1] + offv[i]);
        gload16(bSrc[i] + 64, (char*)Bs[1] + offv[i]);
    }

    f32x4 acc[4][4] = {};

    for (int t = 0; t < nkt; ++t) {
        const int cur = t & 1;
        if (t == nkt - 1) asm volatile("s_waitcnt vmcnt(0)" ::: "memory");
        else              asm volatile("s_waitcnt vmcnt(8)" ::: "memory");
        __builtin_amdgcn_s_barrier();
        __builtin_amdgcn_sched_barrier(0);
        const ushortT* Ac = As[cur];
        const ushortT* Bc = Bs[cur];
        __builtin_amdgcn_s_setprio(1);
#pragma unroll
        for (int kk = 0; kk < 2; ++kk) {
            int g0 = kk * 4 + l4;
            bf16x8 af[4], bfv[4];
#pragma unroll
            for (int mi = 0; mi < 4; ++mi)
                af[mi] = *(const bf16x8*)&Ac[LIX(wm * 64 + mi * 16 + l15, g0)];
#pragma unroll
            for (int ni = 0; ni < 4; ++ni)
                bfv[ni] = *(const bf16x8*)&Bc[LIX(wn * 64 + ni * 16 + l15, g0)];
#pragma unroll
            for (int mi = 0; mi < 4; ++mi)
#pragma unroll
                for (int ni = 0; ni < 4; ++ni)
                    acc[mi][ni] = __builtin_amdgcn_mfma_f32_16x16x32_bf16(
                        bfv[ni], af[mi], acc[mi][ni], 0, 0, 0);   // C^T fragment
        }
        __builtin_amdgcn_s_setprio(0);
        __builtin_amdgcn_s_barrier();
        asm volatile("" ::: "memory");
        if (t + 2 < nkt) {
            int kt2 = (t + 2) << 6;
#pragma unroll
            for (int i = 0; i < 4; ++i) {
                gload16(aSrc[i] + kt2, (char*)As[cur] + offv[i]);
                gload16(bSrc[i] + kt2, (char*)Bs[cur] + offv[i]);
            }
        }
    }

    if (nroute) {
#pragma unroll
        for (int mi = 0; mi < 4; ++mi) {
            int row = r0 + wm * 64 + mi * 16 + l15;
#pragma unroll
            for (int ni = 0; ni < 4; ++ni) {
                int col = c0 + wn * 64 + ni * 16 + l4 * 4;
                int range = col >> 9, cc = col & 511;
                ushortT* d = Db.p[range];
                f32x4 a = acc[mi][ni];
                if ((scmask >> range) & 1) {
                    a[0] *= SCL2; a[1] *= SCL2; a[2] *= SCL2; a[3] *= SCL2;
                }
                if ((vtmask >> range) & 1) {
                    size_t vb = ((size_t)(row >> 9) * Hh + (cc >> 6)) * 64 + (cc & 63);
                    int tok = row & 511;
#pragma unroll
                    for (int r = 0; r < 4; ++r)
                        d[((vb + r) << 9) + tok] = f2bf(a[r]);
                } else {
                    ushort4 o;
                    o.x = f2bf(a[0]); o.y = f2bf(a[1]);
                    o.z = f2bf(a[2]); o.w = f2bf(a[3]);
                    *(ushort4*)&d[((size_t)row << 9) + cc] = o;
                }
            }
        }
    } else {
        const float alp = alpha ? alpha[0] : 1.0f;
        ushortT* outB = Db.p[0];
#pragma unroll
        for (int mi = 0; mi < 4; ++mi) {
            int row = r0 + wm * 64 + mi * 16 + l15;
#pragma unroll
            for (int ni = 0; ni < 4; ++ni) {
                int colb = c0 + wn * 64 + ni * 16 + l4 * 4;
                f32x4 a = acc[mi][ni];
                if (bias) {
                    float4 b4 = *(const float4*)&bias[colb];
                    a[0] += b4.x; a[1] += b4.y; a[2] += b4.z; a[3] += b4.w;
                }
                if (do_relu) {
#pragma unroll
                    for (int r = 0; r < 4; ++r) a[r] = fmaxf(a[r], 0.f);
                }
#pragma unroll
                for (int r = 0; r < 4; ++r) a[r] *= alp;
                size_t idx = (size_t)row * N + colb;
                if (res) {
                    float4 r4 = *(const float4*)&res[idx];
                    a[0] += r4.x; a[1] += r4.y; a[2] += r4.z; a[3] += r4.w;
                }
                if (outF)
                    *(float4*)&outF[idx] = make_float4(a[0], a[1], a[2], a[3]);
                if (outB) {
                    ushort4 o;
                    o.x = f2bf(a[0]); o.y = f2bf(a[1]);
                    o.z = f2bf(a[2]); o.w = f2bf(a[3]);
                    *(ushort4*)&outB[idx] = o;
                }
            }
        }
    }
}

// ---------- 64x128 bf16 MFMA GEMM, T4 double-buffer + T5; res f32/bf16 ----------
__global__ __launch_bounds__(256) void gemm64(
    const ushortT* __restrict__ Bw, const ushortT* __restrict__ A,
    float* __restrict__ outF, ushortT* __restrict__ outB,
    int M, int N, int K, const float* __restrict__ bias,
    const float* __restrict__ resf, const ushortT* __restrict__ resb,
    const float* __restrict__ alpha, int do_relu)
{
    __shared__ __align__(16) ushortT As[2][64 * 64];    // 16 KB
    __shared__ __align__(16) ushortT Bs[2][128 * 64];   // 32 KB
    const int tid = threadIdx.x;
    const int wid = tid >> 6, lane = tid & 63;
    const int wm = wid >> 1, wn = wid & 1;
    const int l15 = lane & 15, l4 = lane >> 4;

    int bid = blockIdx.y * gridDim.x + blockIdx.x;
    int nwg = gridDim.x * gridDim.y;
    int q = nwg >> 3;
    int swz = (bid & 7) * q + (bid >> 3);
    int bx = swz % gridDim.x, by = swz / gridDim.x;
    const int r0 = by * 64, c0 = bx * 128;

    const ushortT* aSrc[2];
    int offA[2];
#pragma unroll
    for (int i = 0; i < 2; ++i) {
        int off = wid * 2048 + i * 1024 + lane * 16;
        int row = off >> 7;
        int sg = ((off >> 4) & 7) ^ (row & 7);
        aSrc[i] = A + (size_t)(r0 + row) * K + sg * 8;
        offA[i] = off;
    }
    const ushortT* bSrc[4];
    int offB[4];
#pragma unroll
    for (int i = 0; i < 4; ++i) {
        int off = wid * 4096 + i * 1024 + lane * 16;
        int row = off >> 7;
        int sg = ((off >> 4) & 7) ^ (row & 7);
        bSrc[i] = Bw + (size_t)(c0 + row) * K + sg * 8;
        offB[i] = off;
    }

    const int nkt = K >> 6;
#pragma unroll
    for (int i = 0; i < 2; ++i) gload16(aSrc[i], (char*)As[0] + offA[i]);
#pragma unroll
    for (int i = 0; i < 4; ++i) gload16(bSrc[i], (char*)Bs[0] + offB[i]);
#pragma unroll
    for (int i = 0; i < 2; ++i) gload16(aSrc[i] + 64, (char*)As[1] + offA[i]);
#pragma unroll
    for (int i = 0; i < 4; ++i) gload16(bSrc[i] + 64, (char*)Bs[1] + offB[i]);

    f32x4 acc[2][4] = {};

    for (int t = 0; t < nkt; ++t) {
        const int cur = t & 1;
        if (t == nkt - 1) asm volatile("s_waitcnt vmcnt(0)" ::: "memory");
        else              asm volatile("s_waitcnt vmcnt(6)" ::: "memory");
        __builtin_amdgcn_s_barrier();
        __builtin_amdgcn_sched_barrier(0);
        const ushortT* Ac = As[cur];
        const ushortT* Bc = Bs[cur];
        __builtin_amdgcn_s_setprio(1);
#pragma unroll
        for (int kk = 0; kk < 2; ++kk) {
            int g0 = kk * 4 + l4;
            bf16x8 af[2], bfv[4];
#pragma unroll
            for (int mi = 0; mi < 2; ++mi)
                af[mi] = *(const bf16x8*)&Ac[LIX(wm * 32 + mi * 16 + l15, g0)];
#pragma unroll
            for (int ni = 0; ni < 4; ++ni)
                bfv[ni] = *(const bf16x8*)&Bc[LIX(wn * 64 + ni * 16 + l15, g0)];
#pragma unroll
            for (int mi = 0; mi < 2; ++mi)
#pragma unroll
                for (int ni = 0; ni < 4; ++ni)
                    acc[mi][ni] = __builtin_amdgcn_mfma_f32_16x16x32_bf16(
                        bfv[ni], af[mi], acc[mi][ni], 0, 0, 0);
        }
        __builtin_amdgcn_s_setprio(0);
        __builtin_amdgcn_s_barrier();
        asm volatile("" ::: "memory");
        if (t + 2 < nkt) {
            int kt2 = (t + 2) << 6;
#pragma unroll
            for (int i = 0; i < 2; ++i) gload16(aSrc[i] + kt2, (char*)As[cur] + offA[i]);
#pragma unroll
            for (int i = 0; i < 4; ++i) gload16(bSrc[i] + kt2, (char*)Bs[cur] + offB[i]);
        }
    }

    const float alp = alpha ? alpha[0] : 1.0f;
#pragma unroll
    for (int mi = 0; mi < 2; ++mi) {
        int row = r0 + wm * 32 + mi * 16 + l15;
#pragma unroll
        for (int ni = 0; ni < 4; ++ni) {
            int colb = c0 + wn * 64 + ni * 16 + l4 * 4;
            f32x4 a = acc[mi][ni];
            if (bias) {
                float4 b4 = *(const float4*)&bias[colb];
                a[0] += b4.x; a[1] += b4.y; a[2] += b4.z; a[3] += b4.w;
            }
            if (do_relu) {
#pragma unroll
                for (int r = 0; r < 4; ++r) a[r] = fmaxf(a[r], 0.f);
            }
#pragma unroll
            for (int r = 0; r < 4; ++r) a[r] *= alp;
            size_t idx = (size_t)row * N + colb;
            if (resf) {
                float4 r4 = *(const float4*)&resf[idx];
                a[0] += r4.x; a[1] += r4.y; a[2] += r4.z; a[3] += r4.w;
            }
            if (resb) {
                ushort4 r4 = *(const ushort4*)&resb[idx];
                a[0] += bf2f(r4.x); a[1] += bf2f(r4.y);
                a[2] += bf2f(r4.z); a[3] += bf2f(r4.w);
            }
            if (outF)
                *(float4*)&outF[idx] = make_float4(a[0], a[1], a[2], a[3]);
            if (outB) {
                ushort4 o;
                o.x = f2bf(a[0]); o.y = f2bf(a[1]);
                o.z = f2bf(a[2]); o.w = f2bf(a[3]);
                *(ushort4*)&outB[idx] = o;
            }
        }
    }
}

// ---------- HA diagonal scores (QD pre-scaled by NORM*log2e) ----------
__global__ __launch_bounds__(256) void diag_dot_bb(const ushortT* __restrict__ QD,
                                                   const ushortT* __restrict__ K,
                                                   float* __restrict__ Sdg) {
    int i = blockIdx.x * 256 + threadIdx.x;
    int h = i & 7, n = (i >> 3) & 511, b = i >> 12;
    int dix = (n < NPICKk) ? n + NPICKk : n - NPICKk;
    const ushortT* q = QD + (((size_t)(b * Nn + n) * Hh + h) << 6);
    const ushortT* k = K + (((size_t)(b * Nn + dix) * Hh + h) << 6);
    float s = 0.f;
#pragma unroll
    for (int d = 0; d < 64; d += 4) {
        ushort4 a = *(const ushort4*)(q + d);
        ushort4 c = *(const ushort4*)(k + d);
        s += bf2f(a.x) * bf2f(c.x) + bf2f(a.y) * bf2f(c.y)
           + bf2f(a.z) * bf2f(c.z) + bf2f(a.w) * bf2f(c.w);
    }
    Sdg[i] = s;
}

// ---------- flash attention: 8 waves / 128 Q-rows per block, shared K/V staging ----------
template <int HA>
__global__ __launch_bounds__(512) void attn11(
    const ushortT* __restrict__ Qm, const ushortT* __restrict__ Km,
    const ushortT* __restrict__ Vtm, const ushortT* __restrict__ QAm,
    const ushortT* __restrict__ QBm, const float* __restrict__ Sdg,
    ushortT* __restrict__ Out)
{
    __shared__ __align__(16) ushortT Ks[64 * 64];        // 8 KB (shared by 8 waves)
    __shared__ __align__(16) ushortT Vs[64 * 64];        // 8 KB
    __shared__ __align__(16) ushortT Pw[8][16 * 64];     // 16 KB, wave-private
    __shared__ float sdl[128];

    const int tid = threadIdx.x, wid = tid >> 6, lane = tid & 63;
    const int l15 = lane & 15, l4 = lane >> 4;

    // XCD-bijective remap over 512 blocks: blocks sharing (b,h) -> same XCD residue
    const int p = blockIdx.x + (blockIdx.y << 2) + (blockIdx.z << 5);
    const int n0 = ((p >> 3) & 3) << 7;                  // 0,128,256,384
    const int g8 = (p & 7) | ((p >> 5) << 3);            // 0..127
    const int h = g8 & 7, b = g8 >> 3;
    const int bh = b * Hh + h;

    // Q/QA/QB fragments direct to registers (wave wid owns rows n0+wid*16 .. +15)
    const size_t qrow = (((size_t)(b * Nn + n0 + wid * 16 + l15) * Hh + h) << 6);
    bf16x8 qf[2], xaf[2], xbf[2];
#pragma unroll
    for (int kk = 0; kk < 2; ++kk) {
        int g0 = kk * 4 + l4;
        qf[kk] = *(const bf16x8*)&Qm[qrow + g0 * 8];
        if (HA) {
            xaf[kk] = *(const bf16x8*)&QAm[qrow + g0 * 8];
            xbf[kk] = *(const bf16x8*)&QBm[qrow + g0 * 8];
        }
    }
    if (HA && tid < 128) sdl[tid] = Sdg[((size_t)(b * Nn + n0 + tid)) * Hh + h];
    // per-wave 64-row group: waves 0-3 -> n0, waves 4-7 -> n0+64
    const int n0g = n0 + ((wid >> 2) << 6);
    const int td = (n0g < NPICKk) ? ((n0g + NPICKk) >> 6) : ((n0g - NPICKk) >> 6);

    // staging: each of 8 waves stages 1 KB of K and 1 KB of V per tile
    const int off = wid * 1024 + lane * 16;
    const int srow = off >> 7, sg = ((off >> 4) & 7) ^ (srow & 7);
    const ushortT* kSrc = Km + (((size_t)(b * Nn + srow) * Hh + h) << 6) + sg * 8;
    ushortT* kDst = (ushortT*)((char*)Ks + off);
    const ushortT* vSrc = Vtm + (((size_t)(bh * 64 + srow)) << 9) + sg * 8;
    ushortT* vDst = (ushortT*)((char*)Vs + off);

    float M[4], Lp[4];
    f32x4 Oa[4] = {};
#pragma unroll
    for (int r = 0; r < 4; ++r) { M[r] = -INFINITY; Lp[r] = 0.f; }

    bf16x8 krbuf[2], vrbuf[2];
    krbuf[0] = *(const bf16x8*)kSrc;
    vrbuf[0] = *(const bf16x8*)vSrc;

#pragma unroll
    for (int t = 0; t < 8; ++t) {
        const int cur = t & 1, nxt = cur ^ 1;
        __builtin_amdgcn_s_barrier();   // all waves done reading Ks/Vs (prev tile)
        *(bf16x8*)kDst = krbuf[cur];
        *(bf16x8*)vDst = vrbuf[cur];
        if (t < 7) {                    // prefetch t+1 (in flight across compute)
            krbuf[nxt] = *(const bf16x8*)(kSrc + (size_t)(t + 1) * (64 * Hh * VDd));
            vrbuf[nxt] = *(const bf16x8*)(vSrc + (t + 1) * 64);
        }
        asm volatile("s_waitcnt lgkmcnt(0)" ::: "memory");
        __builtin_amdgcn_s_barrier();   // all writes visible
        __builtin_amdgcn_sched_barrier(0);

        // ---- S = Q K^T ----
        __builtin_amdgcn_s_setprio(1);
        f32x4 s1[4] = {}, sX[4] = {};
#pragma unroll
        for (int kk = 0; kk < 2; ++kk) {
            bf16x8 aq = qf[kk];
            bf16x8 ax;
            if (HA) ax = (t >= 4) ? xbf[kk] : xaf[kk];
#pragma unroll
            for (int ni = 0; ni < 4; ++ni) {
                bf16x8 bk = *(const bf16x8*)&Ks[LIX(ni * 16 + l15, kk * 4 + l4)];
                s1[ni] = __builtin_amdgcn_mfma_f32_16x16x32_bf16(aq, bk, s1[ni], 0, 0, 0);
                if (HA)
                    sX[ni] = __builtin_amdgcn_mfma_f32_16x16x32_bf16(ax, bk, sX[ni], 0, 0, 0);
            }
        }
        __builtin_amdgcn_s_setprio(0);

        const bool dt = HA && (t == td);

        // ---- lazy max ----
        float mloc[4];
        bool grow = false;
#pragma unroll
        for (int r = 0; r < 4; ++r) {
            int rw = wid * 16 + l4 * 4 + r;        // 0..127, sdl index
            float m = s1[0][r];
#pragma unroll
            for (int ni = 1; ni < 4; ++ni) m = fmaxf(m, s1[ni][r]);
            if (HA) {
#pragma unroll
                for (int ni = 0; ni < 4; ++ni) m = fmaxf(m, sX[ni][r]);
            }
            if (dt && l15 == l4 * 4 + r) m = fmaxf(m, sdl[rw]);
            mloc[r] = m;
            grow = grow || (m > M[r] + 8.f);
        }
        if (__any(grow)) {
#pragma unroll
            for (int r = 0; r < 4; ++r) {
                float m = mloc[r];
#pragma unroll
                for (int o = 8; o >= 1; o >>= 1) m = fmaxf(m, __shfl_xor(m, o, 16));
                float mn = fmaxf(M[r], m);
                float sc = exp2fast(M[r] - mn);
                M[r] = mn; Lp[r] *= sc;
#pragma unroll
                for (int ni = 0; ni < 4; ++ni) Oa[ni][r] *= sc;
            }
        }

        // ---- P = exp2(S - M); per-lane partial L ----
#pragma unroll
        for (int r = 0; r < 4; ++r) {
            int rw = wid * 16 + l4 * 4 + r;
            float rs = 0.f;
#pragma unroll
            for (int ni = 0; ni < 4; ++ni) {
                float pv = exp2fast(s1[ni][r] - M[r]);
                if (HA) pv += exp2fast(sX[ni][r] - M[r]);
                if (dt && ni == (wid & 3) && l15 == l4 * 4 + r)
                    pv += exp2fast(sdl[rw] - M[r]);
                s1[ni][r] = pv;
                rs += pv;
            }
            Lp[r] += rs;
        }

        // ---- write P into wave-private strip (no barrier) ----
#pragma unroll
        for (int ni = 0; ni < 4; ++ni)
#pragma unroll
            for (int r = 0; r < 4; ++r) {
                int prow = l4 * 4 + r;
                int col = ni * 16 + l15;
                Pw[wid][(prow << 6) + ((((col >> 3) ^ (prow & 7))) << 3) + (col & 7)] =
                    f2bf(s1[ni][r]);
            }

        // ---- O += P @ V ----
        __builtin_amdgcn_s_setprio(1);
#pragma unroll
        for (int kk = 0; kk < 2; ++kk) {
            int g0 = kk * 4 + l4;
            bf16x8 ap = *(const bf16x8*)&Pw[wid][LIX(l15, g0)];
#pragma unroll
            for (int ni = 0; ni < 4; ++ni) {
                bf16x8 bv = *(const bf16x8*)&Vs[LIX(ni * 16 + l15, g0)];
                Oa[ni] = __builtin_amdgcn_mfma_f32_16x16x32_bf16(ap, bv, Oa[ni], 0, 0, 0);
            }
        }
        __builtin_amdgcn_s_setprio(0);
    }

#pragma unroll
    for (int r = 0; r < 4; ++r) {
        float l = Lp[r];
#pragma unroll
        for (int o = 8; o >= 1; o >>= 1) l += __shfl_xor(l, o, 16);
        float inv = 1.0f / l;
        size_t obase = (((size_t)(b * Nn + n0 + wid * 16 + l4 * 4 + r) * Hh + h) << 6);
#pragma unroll
        for (int ni = 0; ni < 4; ++ni)
            Out[obase + ni * 16 + l15] = f2bf(Oa[ni][r] * inv);
    }
}

extern "C" void kernel_launch(void* const* d_in, const int* in_sizes, int n_in,
                              void* d_out, int out_size, void* d_ws, size_t ws_size,
                              hipStream_t stream)
{
    const float* x = (const float*)d_in[0];

    int dictOrder = (in_sizes[18] != 512);
    const float* comb_w  = (const float*)d_in[17];
    const float* comb2_w = (const float*)d_in[dictOrder ? 18 : 19];
    const float* comb3_w = (const float*)d_in[dictOrder ? 19 : 21];
    const float* comb_b  = (const float*)d_in[dictOrder ? 20 : 18];
    const float* comb2_b = (const float*)d_in[dictOrder ? 21 : 20];
    const float* comb3_b = (const float*)d_in[22];
    const float* alpha1 = (const float*)d_in[23];
    const float* alpha2 = (const float*)d_in[24];
    const float* alpha3 = (const float*)d_in[25];
    const float* ff1_w1 = (const float*)d_in[26];
    const float* ff1_b1 = (const float*)d_in[27];
    const float* ff1_w2 = (const float*)d_in[28];
    const float* ff1_b2 = (const float*)d_in[29];
    const float* ffa1   = (const float*)d_in[30];
    const float* ff2_w1 = (const float*)d_in[31];
    const float* ff2_b1 = (const float*)d_in[32];
    const float* ff2_w2 = (const float*)d_in[33];
    const float* ff2_b2 = (const float*)d_in[34];
    const float* ffa2   = (const float*)d_in[35];
    const float* ff3_w1 = (const float*)d_in[36];
    const float* ff3_b1 = (const float*)d_in[37];
    const float* ff3_w2 = (const float*)d_in[38];
    const float* ff3_b2 = (const float*)d_in[39];
    const float* ffa3   = (const float*)d_in[40];

    // ---- workspace layout (bytes) ----
    char* W = (char*)d_ws;
    ushortT* wbHead = (ushortT*)(W + 0);
    ushortT* wbMha  = (ushortT*)(W + 4718592);
    ushortT* wbComb = (ushortT*)(W + 8388608);
    ushortT* wbFf1  = (ushortT*)(W + 9961472);
    ushortT* wbFf2  = (ushortT*)(W + 16252928);
    ushortT* xbf    = (ushortT*)(W + 22544384);
    float*   Sd     = (float*)  (W + 30932992);
    ushortT* bufQ   = (ushortT*)(W + 31195136);
    ushortT* bufK   = (ushortT*)(W + 39583744);
    ushortT* bufVt  = (ushortT*)(W + 47972352);
    ushortT* bufQA  = (ushortT*)(W + 56360960);
    ushortT* bufQB  = (ushortT*)(W + 64749568);
    ushortT* bufQD  = (ushortT*)(W + 73138176);
    ushortT* hidden = (ushortT*)(W + 81526784);
    ushortT* curb   = (ushortT*)(W + 115081216);
    ushortT* bufHA  = xbf;
    float*   cur    = (float*)d_out;

    dim3 tb(256);
    const int TOK = Bb * Nn;  // 8192
    const size_t WS = 512 * 512;
    const size_t WF = 2048 * 512;

    // 1. casts / transposes (batched)
    hipLaunchKernelGGL(castx, dim3(TOK * 512 / 1024), tb, 0, stream, x, xbf);
    {
        Ptrs9 s; for (int i = 0; i < 9; ++i) s.p[i] = (const float*)d_in[1 + i];
        hipLaunchKernelGGL(thead, dim3(1, 8, 72), tb, 0, stream, s, wbHead);
    }
    {
        Ptrs10 s;
        for (int i = 0; i < 7; ++i) s.p[i] = (const float*)d_in[10 + i];
        s.p[7] = comb_w; s.p[8] = comb2_w; s.p[9] = comb3_w;
        hipLaunchKernelGGL(tsq, dim3(8, 8, 10), tb, 0, stream, s, wbMha);
    }
    {
        Ptrs6 s;
        s.p[0] = ff1_w1; s.p[1] = ff2_w1; s.p[2] = ff3_w1;
        s.p[3] = ff1_w2; s.p[4] = ff2_w2; s.p[5] = ff3_w2;
        hipLaunchKernelGGL(tff, dim3(32, 32, 6), tb, 0, stream, s, wbFf1);
    }

    auto gemm = [&](PtrsB Bp, PtrsD Db, const ushortT* A, float* oF,
                    int M, int Ncc, int Kc, const float* bias, const float* res,
                    const float* alp, int relu, int nroute, int vtmask, int scmask) {
        hipLaunchKernelGGL(gemm_bf, dim3(Ncc / 128, M / 128), tb, 0, stream,
                           Bp, Db, A, oF, M, Ncc, Kc, bias, res, alp, relu, nroute,
                           vtmask, scmask);
    };
    auto g64 = [&](const ushortT* Bw, const ushortT* A, float* oF, ushortT* oB,
                   int M, int Ncc, int Kc, const float* bias, const float* resf,
                   const ushortT* resb, const float* alp, int relu) {
        hipLaunchKernelGGL(gemm64, dim3(Ncc / 128, M / 64), tb, 0, stream,
                           Bw, A, oF, oB, M, Ncc, Kc, bias, resf, resb, alp, relu);
    };
    auto uni = [&](const ushortT* w) { PtrsB b; for (int i = 0; i < 12; ++i) b.p[i] = w; return b; };
    auto d1 = [&](ushortT* d) { PtrsD dd = {}; dd.p[0] = d; return dd; };

    // 2. HA projections: ONE fused GEMM, N=3072 (Q/QA/QB/QD pre-scaled, scmask=57)
    {
        PtrsB b;
        b.p[0] = b.p[1] = wbHead + 0 * WS;
        b.p[2] = b.p[3] = wbHead + 1 * WS;
        b.p[4] = b.p[5] = wbHead + 2 * WS;
        b.p[6] = wbHead + 4 * WS; b.p[7] = wbHead + 8 * WS;
        b.p[8] = wbHead + 5 * WS; b.p[9] = wbHead + 7 * WS;
        b.p[10] = wbHead + 3 * WS; b.p[11] = wbHead + 6 * WS;
        PtrsD d; d.p[0] = bufQ; d.p[1] = bufK; d.p[2] = bufVt;
        d.p[3] = bufQA; d.p[4] = bufQB; d.p[5] = bufQD;
        gemm(b, d, xbf, nullptr, TOK, 3072, 512, nullptr, nullptr, nullptr, 0, 6, 4, 57);
    }

    // 3. HA attention
    hipLaunchKernelGGL(diag_dot_bb, dim3(Bb * Nn * Hh / 256), tb, 0, stream, bufQD, bufK, Sd);
    hipLaunchKernelGGL((attn11<1>), dim3(Nn / 128, Hh, Bb), dim3(512), 0, stream,
                       bufQ, bufK, bufVt, bufQA, bufQB, Sd, bufHA);

    // 4. comb3 + FF3 (bf16 residual stream)
    g64(wbComb + 2 * WS, bufHA, nullptr, curb, TOK, 512, 512, comb3_b, x, nullptr, alpha3, 0);
    gemm(uni(wbFf1 + 2 * WF), d1(hidden), curb, nullptr, TOK, 2048, 512, ff3_b1, nullptr, nullptr, 1, 0, 0, 0);
    g64(wbFf2 + 2 * WF, hidden, nullptr, curb, TOK, 512, 2048, ff3_b2, nullptr, curb, ffa3, 0);

    // 5. MHA1
    {
        PtrsB b;
        b.p[0] = b.p[1] = wbMha + 0 * WS;
        b.p[2] = b.p[3] = wbMha + 1 * WS;
        b.p[4] = b.p[5] = wbMha + 2 * WS;
        PtrsD d = {}; d.p[0] = bufQ; d.p[1] = bufK; d.p[2] = bufVt;
        gemm(b, d, curb, nullptr, TOK, 1536, 512, nullptr, nullptr, nullptr, 0, 3, 4, 1);
    }
    hipLaunchKernelGGL((attn11<0>), dim3(Nn / 128, Hh, Bb), dim3(512), 0, stream,
                       bufQ, bufK, bufVt, nullptr, nullptr, nullptr, bufHA);
    g64(wbComb + 0 * WS, bufHA, nullptr, curb, TOK, 512, 512, comb_b, nullptr, curb, alpha1, 0);
    gemm(uni(wbFf1 + 0 * WF), d1(hidden), curb, nullptr, TOK, 2048, 512, ff1_b1, nullptr, nullptr, 1, 0, 0, 0);
    g64(wbFf2 + 0 * WF, hidden, nullptr, curb, TOK, 512, 2048, ff1_b2, nullptr, curb, ffa1, 0);

    // 6. MHA2
    {
        PtrsB b;
        b.p[0] = wbMha + 3 * WS; b.p[1] = wbMha + 4 * WS;
        b.p[2] = b.p[3] = wbMha + 5 * WS;
        b.p[4] = b.p[5] = wbMha + 6 * WS;
        PtrsD d = {}; d.p[0] = bufQ; d.p[1] = bufK; d.p[2] = bufVt;
        gemm(b, d, curb, nullptr, TOK, 1536, 512, nullptr, nullptr, nullptr, 0, 3, 4, 1);
    }
    hipLaunchKernelGGL((attn11<0>), dim3(Nn / 128, Hh, Bb), dim3(512), 0, stream,
                       bufQ, bufK, bufVt, nullptr, nullptr, nullptr, bufHA);
    g64(wbComb + 1 * WS, bufHA, nullptr, curb, TOK, 512, 512, comb2_b, nullptr, curb, alpha2, 0);
    gemm(uni(wbFf1 + 1 * WF), d1(hidden), curb, nullptr, TOK, 2048, 512, ff2_b1, nullptr, nullptr, 1, 0, 0, 0);
    // final: write f32 d_out
    g64(wbFf2 + 1 * WF, hidden, cur, nullptr, TOK, 512, 2048, ff2_b2, nullptr, curb, ffa2, 0);
}